// Round 1
// baseline (2188.871 us; speedup 1.0000x reference)
//
#include <hip/hip_runtime.h>
#include <math.h>

// Problem constants
constexpr int BATCH = 4;
constexpr int SEQ   = 4096;
constexpr int DIMC  = 512;
constexpr int NH    = 8;
constexpr int HD    = 64;
constexpr int NLM   = 256;   // landmarks M
constexpr int LWIN  = 16;    // SEQ / NLM
constexpr int KWIN  = 33;
constexpr int BH    = BATCH * NH; // 32

// ---------------------------------------------------------------------------
// K1: qkv = x @ Wqkv, scatter to q/k/v in [b,h,n,d] layout; q scaled by 0.125
// A: [16384, 512] row-major, W: [512, 1536] row-major
// ---------------------------------------------------------------------------
__global__ __launch_bounds__(256) void qkv_gemm(const float* __restrict__ x,
                                                const float* __restrict__ W,
                                                float* __restrict__ qb,
                                                float* __restrict__ kb,
                                                float* __restrict__ vb) {
  __shared__ float As[16][65];
  __shared__ float Bs[16][64];
  const int tid = threadIdx.x;
  const int tx = tid & 15, ty = tid >> 4;
  const int row0 = blockIdx.x * 64;
  const int col0 = blockIdx.y * 64;
  float acc[4][4] = {};
  for (int k0 = 0; k0 < 512; k0 += 16) {
    {
      int i = tid >> 2, kk = (tid & 3) * 4;
      const float4 a = *(const float4*)&x[(size_t)(row0 + i) * 512 + k0 + kk];
      As[kk + 0][i] = a.x; As[kk + 1][i] = a.y; As[kk + 2][i] = a.z; As[kk + 3][i] = a.w;
    }
    {
      int kk = tid >> 4, c = (tid & 15) * 4;
      *(float4*)&Bs[kk][c] = *(const float4*)&W[(size_t)(k0 + kk) * 1536 + col0 + c];
    }
    __syncthreads();
#pragma unroll
    for (int kk = 0; kk < 16; ++kk) {
      float a[4], b[4];
#pragma unroll
      for (int ii = 0; ii < 4; ++ii) a[ii] = As[kk][ty * 4 + ii];
#pragma unroll
      for (int jj = 0; jj < 4; ++jj) b[jj] = Bs[kk][tx * 4 + jj];
#pragma unroll
      for (int ii = 0; ii < 4; ++ii)
#pragma unroll
        for (int jj = 0; jj < 4; ++jj) acc[ii][jj] = fmaf(a[ii], b[jj], acc[ii][jj]);
    }
    __syncthreads();
  }
  const int which = col0 / 512;            // 0=q,1=k,2=v (uniform per block)
  const int h = (col0 % 512) / 64;         // uniform per block
  float* dst = which == 0 ? qb : (which == 1 ? kb : vb);
  const float scale = (which == 0) ? 0.125f : 1.0f;
#pragma unroll
  for (int ii = 0; ii < 4; ++ii) {
    int rg = row0 + ty * 4 + ii;
    int bb = rg >> 12, n = rg & 4095;
    float4 w;
    w.x = acc[ii][0] * scale; w.y = acc[ii][1] * scale;
    w.z = acc[ii][2] * scale; w.w = acc[ii][3] * scale;
    *(float4*)&dst[(((size_t)bb * NH + h) * SEQ + n) * HD + tx * 4] = w;
  }
}

// ---------------------------------------------------------------------------
// K2: landmark mean-pool over windows of 16 along seq
// ---------------------------------------------------------------------------
__global__ void landmark_kernel(const float* __restrict__ src, float* __restrict__ dst) {
  int idx = blockIdx.x * 256 + threadIdx.x;  // BH*NLM*HD = 524288
  int d = idx & 63;
  int m = (idx >> 6) & 255;
  int bh = idx >> 14;
  const float* p = src + ((size_t)bh * SEQ + m * LWIN) * HD + d;
  float s = 0.f;
#pragma unroll
  for (int j = 0; j < LWIN; ++j) s += p[j * HD];
  dst[idx] = s * (1.0f / LWIN);
}

// ---------------------------------------------------------------------------
// K3: attn2 = softmax(q_lm @ k_lm^T) rows; one block per (bh, i)
// ---------------------------------------------------------------------------
__global__ __launch_bounds__(256) void sim2_softmax(const float* __restrict__ qlm,
                                                    const float* __restrict__ klm,
                                                    float* __restrict__ a2) {
  int i = blockIdx.x & 255;
  int bh = blockIdx.x >> 8;
  int j = threadIdx.x;
  __shared__ float qrow[64];
  __shared__ float red[256];
  if (j < 64) qrow[j] = qlm[((size_t)bh * NLM + i) * HD + j];
  __syncthreads();
  const float* kr = klm + ((size_t)bh * NLM + j) * HD;
  float s = 0.f;
#pragma unroll
  for (int d = 0; d < 64; d += 4) {
    float4 kv = *(const float4*)&kr[d];
    s += qrow[d] * kv.x + qrow[d + 1] * kv.y + qrow[d + 2] * kv.z + qrow[d + 3] * kv.w;
  }
  red[j] = s; __syncthreads();
  for (int off = 128; off > 0; off >>= 1) {
    if (j < off) red[j] = fmaxf(red[j], red[j + off]);
    __syncthreads();
  }
  float mx = red[0]; __syncthreads();
  float e = expf(s - mx);
  red[j] = e; __syncthreads();
  for (int off = 128; off > 0; off >>= 1) {
    if (j < off) red[j] += red[j + off];
    __syncthreads();
  }
  float inv = 1.0f / red[0];
  a2[((size_t)bh * NLM + i) * NLM + j] = e * inv;
}

// ---------------------------------------------------------------------------
// K4a: per-bh column sums & row sums of attn2, block-max of each
// ---------------------------------------------------------------------------
__global__ __launch_bounds__(256) void colrow_max(const float* __restrict__ a2,
                                                  float* __restrict__ red) {
  int bh = blockIdx.x;
  int t = threadIdx.x;
  const float* A = a2 + (size_t)bh * NLM * NLM;
  float cs = 0.f, rs = 0.f;
  for (int i = 0; i < NLM; ++i) cs += A[i * NLM + t];
  for (int j = 0; j < NLM; ++j) rs += A[t * NLM + j];
  __shared__ float r1[256], r2[256];
  r1[t] = cs; r2[t] = rs; __syncthreads();
  for (int off = 128; off > 0; off >>= 1) {
    if (t < off) { r1[t] = fmaxf(r1[t], r1[t + off]); r2[t] = fmaxf(r2[t], r2[t + off]); }
    __syncthreads();
  }
  if (t == 0) { red[bh] = r1[0]; red[32 + bh] = r2[0]; }
}

// K4b: combine 32 partials -> invscale at red[64]
__global__ void finalize_scale(float* __restrict__ red) {
  if (threadIdx.x == 0) {
    float m1 = -1e30f, m2 = -1e30f;
    for (int i = 0; i < BH; ++i) { m1 = fmaxf(m1, red[i]); m2 = fmaxf(m2, red[32 + i]); }
    red[64] = 1.0f / (m1 * m2);
  }
}

// K4c: z0 = attn2^T * invscale
__global__ void zinit(const float* __restrict__ a2, const float* __restrict__ red,
                      float* __restrict__ z) {
  int idx = blockIdx.x * 256 + threadIdx.x;  // BH*256*256
  float inv = red[64];
  int i = idx & 255;
  int j = (idx >> 8) & 255;
  int bh = idx >> 16;
  z[idx] = a2[((size_t)bh << 16) + i * 256 + j] * inv;
}

// ---------------------------------------------------------------------------
// K5: batched GEMM  C = coef * (alpha * E - A@B)   (row-major, batched)
// Md,Nd multiples of 64; Kd multiple of 16. Batch strides Md*Kd / Kd*Nd / Md*Nd
// ---------------------------------------------------------------------------
__global__ __launch_bounds__(256) void bgemm(const float* __restrict__ A,
                                             const float* __restrict__ Bm,
                                             const float* __restrict__ E,
                                             float* __restrict__ C,
                                             int Md, int Nd, int Kd,
                                             float alpha, float coef) {
  __shared__ float As[16][65];
  __shared__ float Bs[16][64];
  const int batch = blockIdx.z;
  const float* Ab = A + (size_t)batch * Md * Kd;
  const float* Bb = Bm + (size_t)batch * Kd * Nd;
  const float* Eb = E + (size_t)batch * Md * Nd;
  float* Cb = C + (size_t)batch * Md * Nd;
  const int tid = threadIdx.x;
  const int tx = tid & 15, ty = tid >> 4;
  const int row0 = blockIdx.x * 64;
  const int col0 = blockIdx.y * 64;
  float acc[4][4] = {};
  for (int k0 = 0; k0 < Kd; k0 += 16) {
    {
      int i = tid >> 2, kk = (tid & 3) * 4;
      const float4 a = *(const float4*)&Ab[(size_t)(row0 + i) * Kd + k0 + kk];
      As[kk + 0][i] = a.x; As[kk + 1][i] = a.y; As[kk + 2][i] = a.z; As[kk + 3][i] = a.w;
    }
    {
      int kk = tid >> 4, c = (tid & 15) * 4;
      *(float4*)&Bs[kk][c] = *(const float4*)&Bb[(size_t)(k0 + kk) * Nd + col0 + c];
    }
    __syncthreads();
#pragma unroll
    for (int kk = 0; kk < 16; ++kk) {
      float a[4], b[4];
#pragma unroll
      for (int ii = 0; ii < 4; ++ii) a[ii] = As[kk][ty * 4 + ii];
#pragma unroll
      for (int jj = 0; jj < 4; ++jj) b[jj] = Bs[kk][tx * 4 + jj];
#pragma unroll
      for (int ii = 0; ii < 4; ++ii)
#pragma unroll
        for (int jj = 0; jj < 4; ++jj) acc[ii][jj] = fmaf(a[ii], b[jj], acc[ii][jj]);
    }
    __syncthreads();
  }
#pragma unroll
  for (int ii = 0; ii < 4; ++ii) {
    int rg = row0 + ty * 4 + ii;
    const float4 ev = *(const float4*)&Eb[(size_t)rg * Nd + col0 + tx * 4];
    float4 cv;
    cv.x = coef * (alpha * ev.x - acc[ii][0]);
    cv.y = coef * (alpha * ev.y - acc[ii][1]);
    cv.z = coef * (alpha * ev.z - acc[ii][2]);
    cv.w = coef * (alpha * ev.w - acc[ii][3]);
    *(float4*)&Cb[(size_t)rg * Nd + col0 + tx * 4] = cv;
  }
}

// ---------------------------------------------------------------------------
// K6: sv = softmax(q_lm @ k^T, axis=n) @ v  — flash-style online softmax
// block = 512 threads (8 waves); wave r owns landmark row r0+r; lane = j/d
// ---------------------------------------------------------------------------
__global__ __launch_bounds__(512) void sim3_flash(const float* __restrict__ qlm,
                                                  const float* __restrict__ k,
                                                  const float* __restrict__ v,
                                                  float* __restrict__ sv) {
  constexpr int RG = 8;
  const int bh = blockIdx.y;
  const int r0 = blockIdx.x * RG;
  const int tid = threadIdx.x;
  const int r = tid >> 6;
  const int lane = tid & 63;
  __shared__ float qs[RG][64];
  __shared__ float kt[64][65];
  __shared__ float vt[64][65];
  __shared__ float sp[RG][64];
  qs[r][lane] = qlm[((size_t)bh * NLM + r0 + r) * HD + lane];
  float m = -INFINITY, l = 0.0f, acc = 0.0f;
  const float* kb = k + (size_t)bh * SEQ * HD;
  const float* vb = v + (size_t)bh * SEQ * HD;
  for (int n0 = 0; n0 < SEQ; n0 += 64) {
    __syncthreads();
#pragma unroll
    for (int u = 0; u < 8; ++u) {
      int e = u * 512 + tid;
      int rr = e >> 6, dd = e & 63;
      kt[rr][dd] = kb[(size_t)(n0 + rr) * HD + dd];
      vt[rr][dd] = vb[(size_t)(n0 + rr) * HD + dd];
    }
    __syncthreads();
    float s = 0.f;
#pragma unroll
    for (int dd = 0; dd < 64; ++dd) s = fmaf(qs[r][dd], kt[lane][dd], s);
    float mt = s;
    for (int off = 32; off > 0; off >>= 1) mt = fmaxf(mt, __shfl_xor(mt, off, 64));
    float mn = fmaxf(m, mt);
    float al = expf(m - mn);     // first iter: exp(-inf) = 0
    float p = expf(s - mn);
    float ps = p;
    for (int off = 32; off > 0; off >>= 1) ps += __shfl_xor(ps, off, 64);
    l = l * al + ps;
    sp[r][lane] = p;
    __builtin_amdgcn_wave_barrier();   // keep LDS write before reads (same wave)
    float a2acc = acc * al;
#pragma unroll
    for (int j = 0; j < 64; ++j) a2acc = fmaf(sp[r][j], vt[j][lane], a2acc);
    acc = a2acc;
    m = mn;
  }
  sv[((size_t)bh * NLM + r0 + r) * HD + lane] = acc / l;
}

// ---------------------------------------------------------------------------
// K8: out_pre[b, i, h*64+d] = softmax_j(q_i . k_lm_j) @ tt   (fused attn1)
// block = 256 threads, TR=16 rows per block
// ---------------------------------------------------------------------------
__global__ __launch_bounds__(256) void attn1_apply(const float* __restrict__ q,
                                                   const float* __restrict__ klm,
                                                   const float* __restrict__ tt,
                                                   float* __restrict__ outp) {
  constexpr int TR = 16;
  const int bh = blockIdx.y;
  const int bb = bh >> 3, h = bh & 7;
  const int i0 = blockIdx.x * TR;
  const int tid = threadIdx.x;
  __shared__ float qs[TR][64];      // 4 KB
  __shared__ float S[TR][257];      // 16.4 KB
  __shared__ float cb[128][65];     // 33.3 KB
  __shared__ float rsum[TR];
  const float* qb = q + ((size_t)bh * SEQ + i0) * HD;
#pragma unroll
  for (int u = 0; u < TR * 64 / 256; ++u) {
    int e = u * 256 + tid;
    qs[e >> 6][e & 63] = qb[e];
  }
  // ---- score phase: S[r][j] = q_r . k_lm_j, j in two chunks of 128 ----
  for (int jc = 0; jc < 2; ++jc) {
    __syncthreads();
    const float* kb = klm + ((size_t)bh * NLM + jc * 128) * HD;
    for (int u = 0; u < 32; ++u) {
      int e = u * 256 + tid;
      cb[e >> 6][e & 63] = kb[e];
    }
    __syncthreads();
    int jj = tid & 127;
    int rb = (tid >> 7) * 8;
    float sacc[8];
#pragma unroll
    for (int rr = 0; rr < 8; ++rr) sacc[rr] = 0.f;
    for (int dd = 0; dd < 64; ++dd) {
      float kv = cb[jj][dd];
#pragma unroll
      for (int rr = 0; rr < 8; ++rr) sacc[rr] = fmaf(qs[rb + rr][dd], kv, sacc[rr]);
    }
#pragma unroll
    for (int rr = 0; rr < 8; ++rr) S[rb + rr][jc * 128 + jj] = sacc[rr];
  }
  __syncthreads();
  // ---- softmax over 256 per row: 16 threads per row ----
  {
    int r = tid >> 4, kk = tid & 15;
    float mx = -INFINITY;
    for (int j = kk; j < 256; j += 16) mx = fmaxf(mx, S[r][j]);
    for (int off = 1; off < 16; off <<= 1) mx = fmaxf(mx, __shfl_xor(mx, off, 64));
    float sm = 0.f;
    for (int j = kk; j < 256; j += 16) {
      float e = expf(S[r][j] - mx);
      S[r][j] = e;
      sm += e;
    }
    for (int off = 1; off < 16; off <<= 1) sm += __shfl_xor(sm, off, 64);
    if (kk == 0) rsum[r] = sm;
  }
  __syncthreads();
  // ---- accumulate: out[r][d] = sum_j p_j * tt[j][d] (then /rsum) ----
  float accv[4] = {};
  const float* tb = tt + (size_t)bh * NLM * HD;
  int d = tid & 63, g = tid >> 6;
  int r0 = g * 4;
  for (int jc = 0; jc < 2; ++jc) {
    __syncthreads();
    for (int u = 0; u < 32; ++u) {
      int e = u * 256 + tid;
      cb[e >> 6][e & 63] = tb[jc * 128 * 64 + e];
    }
    __syncthreads();
    for (int jl = 0; jl < 128; ++jl) {
      float vv = cb[jl][d];
#pragma unroll
      for (int rr = 0; rr < 4; ++rr)
        accv[rr] = fmaf(S[r0 + rr][jc * 128 + jl], vv, accv[rr]);
    }
  }
#pragma unroll
  for (int rr = 0; rr < 4; ++rr) {
    int i = i0 + r0 + rr;
    outp[((size_t)bb * SEQ + i) * DIMC + h * HD + d] = accv[rr] / rsum[r0 + rr];
  }
}

// ---------------------------------------------------------------------------
// K9: depthwise residual conv along seq, added into out_pre
// ---------------------------------------------------------------------------
__global__ void conv_add(const float* __restrict__ v, const float* __restrict__ kern,
                         float* __restrict__ outp) {
  int idx = blockIdx.x * 256 + threadIdx.x;  // BH*SEQ*HD
  int d = idx & 63;
  int n = (idx >> 6) & 4095;
  int bh = idx >> 18;
  int bb = bh >> 3, h = bh & 7;
  __shared__ float ks[KWIN];
  if (threadIdx.x < KWIN) ks[threadIdx.x] = kern[h * KWIN + threadIdx.x];
  __syncthreads();
  const float* vb = v + (size_t)bh * SEQ * HD;
  float s = 0.f;
#pragma unroll
  for (int t = 0; t < KWIN; ++t) {
    int nn = n + t - (KWIN / 2);
    if (nn >= 0 && nn < SEQ) s = fmaf(ks[t], vb[(size_t)nn * HD + d], s);
  }
  size_t o = ((size_t)bb * SEQ + n) * DIMC + h * HD + d;
  outp[o] += s;
}

// ---------------------------------------------------------------------------
// K10: d_out = out_pre @ Wout + bout   [16384,512] @ [512,512]
// ---------------------------------------------------------------------------
__global__ __launch_bounds__(256) void out_gemm(const float* __restrict__ Ain,
                                                const float* __restrict__ W,
                                                const float* __restrict__ bias,
                                                float* __restrict__ Cout) {
  __shared__ float As[16][65];
  __shared__ float Bs[16][64];
  const int tid = threadIdx.x;
  const int tx = tid & 15, ty = tid >> 4;
  const int row0 = blockIdx.x * 64;
  const int col0 = blockIdx.y * 64;
  float acc[4][4] = {};
  for (int k0 = 0; k0 < 512; k0 += 16) {
    {
      int i = tid >> 2, kk = (tid & 3) * 4;
      const float4 a = *(const float4*)&Ain[(size_t)(row0 + i) * 512 + k0 + kk];
      As[kk + 0][i] = a.x; As[kk + 1][i] = a.y; As[kk + 2][i] = a.z; As[kk + 3][i] = a.w;
    }
    {
      int kk = tid >> 4, c = (tid & 15) * 4;
      *(float4*)&Bs[kk][c] = *(const float4*)&W[(size_t)(k0 + kk) * 512 + col0 + c];
    }
    __syncthreads();
#pragma unroll
    for (int kk = 0; kk < 16; ++kk) {
      float a[4], b[4];
#pragma unroll
      for (int ii = 0; ii < 4; ++ii) a[ii] = As[kk][ty * 4 + ii];
#pragma unroll
      for (int jj = 0; jj < 4; ++jj) b[jj] = Bs[kk][tx * 4 + jj];
#pragma unroll
      for (int ii = 0; ii < 4; ++ii)
#pragma unroll
        for (int jj = 0; jj < 4; ++jj) acc[ii][jj] = fmaf(a[ii], b[jj], acc[ii][jj]);
    }
    __syncthreads();
  }
  const int cbase = col0 + tx * 4;
  const float4 bv = *(const float4*)&bias[cbase];
#pragma unroll
  for (int ii = 0; ii < 4; ++ii) {
    int rg = row0 + ty * 4 + ii;
    float4 o;
    o.x = acc[ii][0] + bv.x; o.y = acc[ii][1] + bv.y;
    o.z = acc[ii][2] + bv.z; o.w = acc[ii][3] + bv.w;
    *(float4*)&Cout[(size_t)rg * 512 + cbase] = o;
  }
}

// ---------------------------------------------------------------------------
extern "C" void kernel_launch(void* const* d_in, const int* in_sizes, int n_in,
                              void* d_out, int out_size, void* d_ws, size_t ws_size,
                              hipStream_t stream) {
  const float* x    = (const float*)d_in[0];
  const float* Wqkv = (const float*)d_in[1];
  const float* Wout = (const float*)d_in[2];
  const float* bout = (const float*)d_in[3];
  const float* rker = (const float*)d_in[4];
  float* out = (float*)d_out;
  float* ws = (float*)d_ws;

  // workspace layout (float element offsets) — total ~193 MB
  float* q    = ws;                 // 8388608
  float* k    = ws + 8388608;       // 8388608
  float* v    = ws + 16777216;      // 8388608
  float* qlm  = ws + 25165824;      // 524288
  float* klm  = ws + 25690112;      // 524288
  float* a2   = ws + 26214400;      // 2097152
  float* za   = ws + 28311552;      // 2097152
  float* zb   = ws + 30408704;      // 2097152
  float* xz   = ws + 32505856;      // 2097152
  float* t2   = ws + 34603008;      // 2097152
  float* t3   = ws + 36700160;      // 2097152
  float* sv   = ws + 38797312;      // 524288
  float* tt   = ws + 39321600;      // 524288
  float* outp = ws + 39845888;      // 8388608
  float* red  = ws + 48234496;      // 128

  qkv_gemm<<<dim3(256, 24), 256, 0, stream>>>(x, Wqkv, q, k, v);
  landmark_kernel<<<2048, 256, 0, stream>>>(q, qlm);
  landmark_kernel<<<2048, 256, 0, stream>>>(k, klm);
  sim2_softmax<<<8192, 256, 0, stream>>>(qlm, klm, a2);
  colrow_max<<<32, 256, 0, stream>>>(a2, red);
  finalize_scale<<<1, 64, 0, stream>>>(red);
  zinit<<<8192, 256, 0, stream>>>(a2, red, za);

  float* zc = za;
  float* zn = zb;
  for (int it = 0; it < 6; ++it) {
    // xz = a2 @ z
    bgemm<<<dim3(4, 4, 32), 256, 0, stream>>>(a2, zc, a2, xz, 256, 256, 256, 0.f, -1.f);
    // t2 = 7*xz - xz@xz
    bgemm<<<dim3(4, 4, 32), 256, 0, stream>>>(xz, xz, xz, t2, 256, 256, 256, 7.f, 1.f);
    // t3 = 15*xz - xz@t2
    bgemm<<<dim3(4, 4, 32), 256, 0, stream>>>(xz, t2, xz, t3, 256, 256, 256, 15.f, 1.f);
    // zn = 0.25*(13*z - z@t3)
    bgemm<<<dim3(4, 4, 32), 256, 0, stream>>>(zc, t3, zc, zn, 256, 256, 256, 13.f, 0.25f);
    float* tp = zc; zc = zn; zn = tp;
  }
  // after 6 swaps zc == za again (attn2_inv)

  sim3_flash<<<dim3(32, 32), 512, 0, stream>>>(qlm, k, v, sv);
  // tt = attn2_inv @ sv
  bgemm<<<dim3(4, 1, 32), 256, 0, stream>>>(zc, sv, zc, tt, 256, 64, 256, 0.f, -1.f);
  attn1_apply<<<dim3(256, 32), 256, 0, stream>>>(q, klm, tt, outp);
  conv_add<<<32768, 256, 0, stream>>>(v, rker, outp);
  out_gemm<<<dim3(256, 8), 256, 0, stream>>>(outp, Wout, bout, out);
}

// Round 2
// 1626.451 us; speedup vs baseline: 1.3458x; 1.3458x over previous
//
#include <hip/hip_runtime.h>
#include <math.h>

// Problem constants
constexpr int BATCH = 4;
constexpr int SEQ   = 4096;
constexpr int DIMC  = 512;
constexpr int NH    = 8;
constexpr int HD    = 64;
constexpr int NLM   = 256;   // landmarks M
constexpr int LWIN  = 16;    // SEQ / NLM
constexpr int KWIN  = 33;
constexpr int BH    = BATCH * NH; // 32

typedef __attribute__((ext_vector_type(8))) short  bfrag;  // 8 bf16 for MFMA A/B
typedef __attribute__((ext_vector_type(4))) float  ffrag;  // MFMA C/D
typedef __attribute__((ext_vector_type(8))) unsigned short us8;
typedef __attribute__((ext_vector_type(4))) unsigned short us4;

__device__ __forceinline__ unsigned short f2bf(float f) {
  unsigned u = __builtin_bit_cast(unsigned, f);
  return (unsigned short)((u + 0x7FFFu + ((u >> 16) & 1u)) >> 16);
}
__device__ __forceinline__ float bf2f(unsigned short h) {
  unsigned u = ((unsigned)h) << 16;
  return __builtin_bit_cast(float, u);
}

// ---------------------------------------------------------------------------
// K1: qkv = x @ Wqkv, scatter to q/k/v in [b,h,n,d] layout; q scaled by 0.125
// ---------------------------------------------------------------------------
__global__ __launch_bounds__(256) void qkv_gemm(const float* __restrict__ x,
                                                const float* __restrict__ W,
                                                float* __restrict__ qb,
                                                float* __restrict__ kb,
                                                float* __restrict__ vb) {
  __shared__ float As[16][65];
  __shared__ float Bs[16][64];
  const int tid = threadIdx.x;
  const int tx = tid & 15, ty = tid >> 4;
  const int row0 = blockIdx.x * 64;
  const int col0 = blockIdx.y * 64;
  float acc[4][4] = {};
  for (int k0 = 0; k0 < 512; k0 += 16) {
    {
      int i = tid >> 2, kk = (tid & 3) * 4;
      const float4 a = *(const float4*)&x[(size_t)(row0 + i) * 512 + k0 + kk];
      As[kk + 0][i] = a.x; As[kk + 1][i] = a.y; As[kk + 2][i] = a.z; As[kk + 3][i] = a.w;
    }
    {
      int kk = tid >> 4, c = (tid & 15) * 4;
      *(float4*)&Bs[kk][c] = *(const float4*)&W[(size_t)(k0 + kk) * 1536 + col0 + c];
    }
    __syncthreads();
#pragma unroll
    for (int kk = 0; kk < 16; ++kk) {
      float a[4], b[4];
#pragma unroll
      for (int ii = 0; ii < 4; ++ii) a[ii] = As[kk][ty * 4 + ii];
#pragma unroll
      for (int jj = 0; jj < 4; ++jj) b[jj] = Bs[kk][tx * 4 + jj];
#pragma unroll
      for (int ii = 0; ii < 4; ++ii)
#pragma unroll
        for (int jj = 0; jj < 4; ++jj) acc[ii][jj] = fmaf(a[ii], b[jj], acc[ii][jj]);
    }
    __syncthreads();
  }
  const int which = col0 / 512;
  const int h = (col0 % 512) / 64;
  float* dst = which == 0 ? qb : (which == 1 ? kb : vb);
  const float scale = (which == 0) ? 0.125f : 1.0f;
#pragma unroll
  for (int ii = 0; ii < 4; ++ii) {
    int rg = row0 + ty * 4 + ii;
    int bb = rg >> 12, n = rg & 4095;
    float4 w;
    w.x = acc[ii][0] * scale; w.y = acc[ii][1] * scale;
    w.z = acc[ii][2] * scale; w.w = acc[ii][3] * scale;
    *(float4*)&dst[(((size_t)bb * NH + h) * SEQ + n) * HD + tx * 4] = w;
  }
}

// ---------------------------------------------------------------------------
// K2: landmark mean-pool over windows of 16 along seq
// ---------------------------------------------------------------------------
__global__ void landmark_kernel(const float* __restrict__ src, float* __restrict__ dst) {
  int idx = blockIdx.x * 256 + threadIdx.x;
  int d = idx & 63;
  int m = (idx >> 6) & 255;
  int bh = idx >> 14;
  const float* p = src + ((size_t)bh * SEQ + m * LWIN) * HD + d;
  float s = 0.f;
#pragma unroll
  for (int j = 0; j < LWIN; ++j) s += p[j * HD];
  dst[idx] = s * (1.0f / LWIN);
}

// ---------------------------------------------------------------------------
// K3: attn2 = softmax(q_lm @ k_lm^T) rows (fp32, feeds pinv -> keep exact)
// ---------------------------------------------------------------------------
__global__ __launch_bounds__(256) void sim2_softmax(const float* __restrict__ qlm,
                                                    const float* __restrict__ klm,
                                                    float* __restrict__ a2) {
  int i = blockIdx.x & 255;
  int bh = blockIdx.x >> 8;
  int j = threadIdx.x;
  __shared__ float qrow[64];
  __shared__ float red[256];
  if (j < 64) qrow[j] = qlm[((size_t)bh * NLM + i) * HD + j];
  __syncthreads();
  const float* kr = klm + ((size_t)bh * NLM + j) * HD;
  float s = 0.f;
#pragma unroll
  for (int d = 0; d < 64; d += 4) {
    float4 kv = *(const float4*)&kr[d];
    s += qrow[d] * kv.x + qrow[d + 1] * kv.y + qrow[d + 2] * kv.z + qrow[d + 3] * kv.w;
  }
  red[j] = s; __syncthreads();
  for (int off = 128; off > 0; off >>= 1) {
    if (j < off) red[j] = fmaxf(red[j], red[j + off]);
    __syncthreads();
  }
  float mx = red[0]; __syncthreads();
  float e = expf(s - mx);
  red[j] = e; __syncthreads();
  for (int off = 128; off > 0; off >>= 1) {
    if (j < off) red[j] += red[j + off];
    __syncthreads();
  }
  float inv = 1.0f / red[0];
  a2[((size_t)bh * NLM + i) * NLM + j] = e * inv;
}

// ---------------------------------------------------------------------------
// K4a/b/c: pinv init scale + z0
// ---------------------------------------------------------------------------
__global__ __launch_bounds__(256) void colrow_max(const float* __restrict__ a2,
                                                  float* __restrict__ red) {
  int bh = blockIdx.x;
  int t = threadIdx.x;
  const float* A = a2 + (size_t)bh * NLM * NLM;
  float cs = 0.f, rs = 0.f;
  for (int i = 0; i < NLM; ++i) cs += A[i * NLM + t];
  for (int j = 0; j < NLM; ++j) rs += A[t * NLM + j];
  __shared__ float r1[256], r2[256];
  r1[t] = cs; r2[t] = rs; __syncthreads();
  for (int off = 128; off > 0; off >>= 1) {
    if (t < off) { r1[t] = fmaxf(r1[t], r1[t + off]); r2[t] = fmaxf(r2[t], r2[t + off]); }
    __syncthreads();
  }
  if (t == 0) { red[bh] = r1[0]; red[32 + bh] = r2[0]; }
}

__global__ void finalize_scale(float* __restrict__ red) {
  if (threadIdx.x == 0) {
    float m1 = -1e30f, m2 = -1e30f;
    for (int i = 0; i < BH; ++i) { m1 = fmaxf(m1, red[i]); m2 = fmaxf(m2, red[32 + i]); }
    red[64] = 1.0f / (m1 * m2);
  }
}

__global__ void zinit(const float* __restrict__ a2, const float* __restrict__ red,
                      float* __restrict__ z) {
  int idx = blockIdx.x * 256 + threadIdx.x;
  float inv = red[64];
  int i = idx & 255;
  int j = (idx >> 8) & 255;
  int bh = idx >> 16;
  z[idx] = a2[((size_t)bh << 16) + i * 256 + j] * inv;
}

// ---------------------------------------------------------------------------
// K5: split-bf16 MFMA batched GEMM:  C = coef * (alpha * E - A@B)
// A[M,K], B[K,N] row-major fp32; internal bf16 hi/lo split (3-product) for
// fp32-class accuracy. BM=BN=64, BK=32. 256 threads, 4 waves (16-row strips).
// ---------------------------------------------------------------------------
__global__ __launch_bounds__(256) void bgemm_mfma3(const float* __restrict__ A,
                                                   const float* __restrict__ B,
                                                   const float* E,
                                                   float* C,
                                                   int Md, int Nd, int Kd,
                                                   float alpha, float coef) {
  __shared__ unsigned short Ah[64][40], Al[64][40];
  __shared__ unsigned short Bhs[64][40], Bls[64][40];  // [n][k]
  __shared__ float Bf[32][68];                          // bounce [k][n]
  const int batch = blockIdx.z;
  const float* Ab = A + (size_t)batch * Md * Kd;
  const float* Bb = B + (size_t)batch * Kd * Nd;
  const float* Eb = E + (size_t)batch * Md * Nd;
  float* Cb = C + (size_t)batch * Md * Nd;
  const int tid = threadIdx.x;
  const int w = tid >> 6, lane = tid & 63;
  const int lm = lane & 15, lq = lane >> 4;
  const int row0 = blockIdx.x * 64, col0 = blockIdx.y * 64;
  const ffrag fz = {0.f, 0.f, 0.f, 0.f};
  ffrag acc[4] = {fz, fz, fz, fz};

  for (int k0 = 0; k0 < Kd; k0 += 32) {
    __syncthreads();  // prior-iter frag reads done before overwrite
    {   // stage A 64x32 -> hi/lo
      int m = tid >> 2, kk = (tid & 3) * 8;
      const float4 f0 = *(const float4*)&Ab[(size_t)(row0 + m) * Kd + k0 + kk];
      const float4 f1 = *(const float4*)&Ab[(size_t)(row0 + m) * Kd + k0 + kk + 4];
      float fs[8] = {f0.x, f0.y, f0.z, f0.w, f1.x, f1.y, f1.z, f1.w};
      us8 hi, lo;
#pragma unroll
      for (int j = 0; j < 8; ++j) {
        unsigned short h = f2bf(fs[j]);
        hi[j] = h;
        lo[j] = f2bf(fs[j] - bf2f(h));
      }
      *(us8*)&Ah[m][kk] = hi;
      *(us8*)&Al[m][kk] = lo;
    }
    {   // stage B 32x64 into fp32 bounce (coalesced)
      int kk = tid >> 3, n0 = (tid & 7) * 8;
      const float4 g0 = *(const float4*)&Bb[(size_t)(k0 + kk) * Nd + col0 + n0];
      const float4 g1 = *(const float4*)&Bb[(size_t)(k0 + kk) * Nd + col0 + n0 + 4];
      *(float4*)&Bf[kk][n0] = g0;
      *(float4*)&Bf[kk][n0 + 4] = g1;
    }
    __syncthreads();
    {   // transpose-split B -> [n][k] hi/lo
      int n = tid >> 2, kk = (tid & 3) * 8;
      us8 hi, lo;
#pragma unroll
      for (int j = 0; j < 8; ++j) {
        float f = Bf[kk + j][n];
        unsigned short h = f2bf(f);
        hi[j] = h;
        lo[j] = f2bf(f - bf2f(h));
      }
      *(us8*)&Bhs[n][kk] = hi;
      *(us8*)&Bls[n][kk] = lo;
    }
    __syncthreads();
    bfrag ah = *(const bfrag*)&Ah[16 * w + lm][8 * lq];
    bfrag al = *(const bfrag*)&Al[16 * w + lm][8 * lq];
#pragma unroll
    for (int t = 0; t < 4; ++t) {
      bfrag bh = *(const bfrag*)&Bhs[16 * t + lm][8 * lq];
      bfrag bl = *(const bfrag*)&Bls[16 * t + lm][8 * lq];
      acc[t] = __builtin_amdgcn_mfma_f32_16x16x32_bf16(ah, bh, acc[t], 0, 0, 0);
      acc[t] = __builtin_amdgcn_mfma_f32_16x16x32_bf16(al, bh, acc[t], 0, 0, 0);
      acc[t] = __builtin_amdgcn_mfma_f32_16x16x32_bf16(ah, bl, acc[t], 0, 0, 0);
    }
  }
#pragma unroll
  for (int t = 0; t < 4; ++t)
#pragma unroll
    for (int r = 0; r < 4; ++r) {
      int m = row0 + 16 * w + 4 * lq + r;
      int n = col0 + 16 * t + lm;
      float e = Eb[(size_t)m * Nd + n];
      Cb[(size_t)m * Nd + n] = coef * (alpha * e - acc[t][r]);
    }
}

// ---------------------------------------------------------------------------
// convert helpers: fp32 -> bf16 flat; v -> v^T bf16
// ---------------------------------------------------------------------------
__global__ void cvt_bf16_flat(const float* __restrict__ src, unsigned short* __restrict__ dst,
                              int n4) {
  int i = blockIdx.x * 256 + threadIdx.x;
  if (i >= n4) return;
  float4 f = ((const float4*)src)[i];
  us4 o;
  o[0] = f2bf(f.x); o[1] = f2bf(f.y); o[2] = f2bf(f.z); o[3] = f2bf(f.w);
  ((us4*)dst)[i] = o;
}

__global__ __launch_bounds__(256) void vT_cvt(const float* __restrict__ v,
                                              unsigned short* __restrict__ vT) {
  __shared__ float Ts[64][68];
  const int bh = blockIdx.y;
  const int n0 = blockIdx.x * 64;   // grid (64, 32)
  const int tid = threadIdx.x;
  {
    int n = tid >> 2, off = (tid & 3) * 16;
#pragma unroll
    for (int u = 0; u < 4; ++u)
      *(float4*)&Ts[n][off + 4 * u] =
          *(const float4*)&v[((size_t)bh * SEQ + n0 + n) * HD + off + 4 * u];
  }
  __syncthreads();
  {
    int d = tid >> 2, nn0 = (tid & 3) * 16;
    us8 o0, o1;
#pragma unroll
    for (int j = 0; j < 8; ++j) o0[j] = f2bf(Ts[nn0 + j][d]);
#pragma unroll
    for (int j = 0; j < 8; ++j) o1[j] = f2bf(Ts[nn0 + 8 + j][d]);
    unsigned short* dst = &vT[((size_t)bh * HD + d) * SEQ + n0 + nn0];
    *(us8*)dst = o0;
    *(us8*)&dst[8] = o1;
  }
}

// ---------------------------------------------------------------------------
// K6: sim3 flash via MFMA, NO max-subtraction (|S| <= |q_lm||k| << 1 so
// exp(S)/sum exp(S) == softmax exactly). n-axis split into NCH chunks,
// partials combined by sim3_finalize (deterministic).
// grid: (4 mblocks, NCH, 32 bh), 256 threads.
// ---------------------------------------------------------------------------
constexpr int NCH = 4;
__global__ __launch_bounds__(256) void sim3_mfma(const unsigned short* __restrict__ qlm_bf,
                                                 const unsigned short* __restrict__ k_bf,
                                                 const unsigned short* __restrict__ vT_bf,
                                                 float* __restrict__ O_part,
                                                 float* __restrict__ l_part) {
  constexpr int CHUNK = SEQ / NCH;  // 1024
  __shared__ unsigned short Qs[64][72];
  __shared__ unsigned short Ks[128][72];
  __shared__ unsigned short Vs[64][136];
  __shared__ unsigned short Ps[64][136];
  const int bh = blockIdx.z;
  const int m0 = blockIdx.x * 64;
  const int n_base = blockIdx.y * CHUNK;
  const int tid = threadIdx.x;
  const int w = tid >> 6, lane = tid & 63;
  const int lm = lane & 15, lq = lane >> 4;
  {
    int m = tid >> 2, off = (tid & 3) * 16;
    const unsigned short* src = &qlm_bf[((size_t)bh * NLM + m0 + m) * HD + off];
    *(us8*)&Qs[m][off] = *(const us8*)src;
    *(us8*)&Qs[m][off + 8] = *(const us8*)&src[8];
  }
  const ffrag fz = {0.f, 0.f, 0.f, 0.f};
  ffrag O[4] = {fz, fz, fz, fz};
  float lsum[4] = {0.f, 0.f, 0.f, 0.f};

  for (int n0 = 0; n0 < CHUNK; n0 += 128) {
    __syncthreads();
    {   // stage Ks [128][64]
      int n = tid >> 1, off = (tid & 1) * 32;
      const unsigned short* src = &k_bf[((size_t)bh * SEQ + n_base + n0 + n) * HD + off];
#pragma unroll
      for (int u = 0; u < 4; ++u) *(us8*)&Ks[n][off + 8 * u] = *(const us8*)&src[8 * u];
    }
    {   // stage Vs [64][128] from v^T
      int d = tid >> 2, off = (tid & 3) * 32;
      const unsigned short* src = &vT_bf[((size_t)bh * HD + d) * SEQ + n_base + n0 + off];
#pragma unroll
      for (int u = 0; u < 4; ++u) *(us8*)&Vs[d][off + 8 * u] = *(const us8*)&src[8 * u];
    }
    __syncthreads();
    ffrag S[8] = {fz, fz, fz, fz, fz, fz, fz, fz};
#pragma unroll
    for (int ks = 0; ks < 2; ++ks) {
      bfrag a = *(const bfrag*)&Qs[16 * w + lm][32 * ks + 8 * lq];
#pragma unroll
      for (int t = 0; t < 8; ++t) {
        bfrag b = *(const bfrag*)&Ks[16 * t + lm][32 * ks + 8 * lq];
        S[t] = __builtin_amdgcn_mfma_f32_16x16x32_bf16(a, b, S[t], 0, 0, 0);
      }
    }
#pragma unroll
    for (int t = 0; t < 8; ++t)
#pragma unroll
      for (int r = 0; r < 4; ++r) {
        float p = __expf(S[t][r]);
        lsum[r] += p;
        Ps[16 * w + 4 * lq + r][16 * t + lm] = f2bf(p);
      }
    __syncthreads();
#pragma unroll
    for (int kk = 0; kk < 4; ++kk) {
      bfrag a = *(const bfrag*)&Ps[16 * w + lm][32 * kk + 8 * lq];
#pragma unroll
      for (int t2 = 0; t2 < 4; ++t2) {
        bfrag b = *(const bfrag*)&Vs[16 * t2 + lm][32 * kk + 8 * lq];
        O[t2] = __builtin_amdgcn_mfma_f32_16x16x32_bf16(a, b, O[t2], 0, 0, 0);
      }
    }
  }
  // reduce row-sums across the 16-lane (lm) group
#pragma unroll
  for (int r = 0; r < 4; ++r) {
#pragma unroll
    for (int off = 1; off < 16; off <<= 1) lsum[r] += __shfl_xor(lsum[r], off, 64);
  }
  const size_t pbase = (size_t)blockIdx.y * 32 + bh;
  if (lm == 0) {
#pragma unroll
    for (int r = 0; r < 4; ++r)
      l_part[pbase * NLM + m0 + 16 * w + 4 * lq + r] = lsum[r];
  }
#pragma unroll
  for (int t2 = 0; t2 < 4; ++t2)
#pragma unroll
    for (int r = 0; r < 4; ++r) {
      int m = m0 + 16 * w + 4 * lq + r;
      int d = 16 * t2 + lm;
      O_part[(pbase * NLM + m) * HD + d] = O[t2][r];
    }
}

__global__ void sim3_finalize(const float* __restrict__ O_part,
                              const float* __restrict__ l_part,
                              float* __restrict__ sv) {
  int idx = blockIdx.x * 256 + threadIdx.x;  // BH*NLM*HD = 524288
  int m = (idx >> 6) & 255;
  int bh = idx >> 14;
  float o = 0.f, l = 0.f;
#pragma unroll
  for (int c = 0; c < NCH; ++c) {
    o += O_part[((size_t)(c * 32 + bh) << 14) + (idx & 16383)];
    l += l_part[(size_t)(c * 32 + bh) * NLM + m];
  }
  sv[idx] = o / l;
}

// ---------------------------------------------------------------------------
// K8: fused attn1 (fp32): out_pre = softmax(q @ klm^T) @ tt
// ---------------------------------------------------------------------------
__global__ __launch_bounds__(256) void attn1_apply(const float* __restrict__ q,
                                                   const float* __restrict__ klm,
                                                   const float* __restrict__ tt,
                                                   float* __restrict__ outp) {
  constexpr int TR = 16;
  const int bh = blockIdx.y;
  const int bb = bh >> 3, h = bh & 7;
  const int i0 = blockIdx.x * TR;
  const int tid = threadIdx.x;
  __shared__ float qs[TR][64];
  __shared__ float S[TR][257];
  __shared__ float cb[128][65];
  __shared__ float rsum[TR];
  const float* qb = q + ((size_t)bh * SEQ + i0) * HD;
#pragma unroll
  for (int u = 0; u < TR * 64 / 256; ++u) {
    int e = u * 256 + tid;
    qs[e >> 6][e & 63] = qb[e];
  }
  for (int jc = 0; jc < 2; ++jc) {
    __syncthreads();
    const float* kb = klm + ((size_t)bh * NLM + jc * 128) * HD;
    for (int u = 0; u < 32; ++u) {
      int e = u * 256 + tid;
      cb[e >> 6][e & 63] = kb[e];
    }
    __syncthreads();
    int jj = tid & 127;
    int rb = (tid >> 7) * 8;
    float sacc[8];
#pragma unroll
    for (int rr = 0; rr < 8; ++rr) sacc[rr] = 0.f;
    for (int dd = 0; dd < 64; ++dd) {
      float kv = cb[jj][dd];
#pragma unroll
      for (int rr = 0; rr < 8; ++rr) sacc[rr] = fmaf(qs[rb + rr][dd], kv, sacc[rr]);
    }
#pragma unroll
    for (int rr = 0; rr < 8; ++rr) S[rb + rr][jc * 128 + jj] = sacc[rr];
  }
  __syncthreads();
  {
    int r = tid >> 4, kk = tid & 15;
    float mx = -INFINITY;
    for (int j = kk; j < 256; j += 16) mx = fmaxf(mx, S[r][j]);
    for (int off = 1; off < 16; off <<= 1) mx = fmaxf(mx, __shfl_xor(mx, off, 64));
    float sm = 0.f;
    for (int j = kk; j < 256; j += 16) {
      float e = expf(S[r][j] - mx);
      S[r][j] = e;
      sm += e;
    }
    for (int off = 1; off < 16; off <<= 1) sm += __shfl_xor(sm, off, 64);
    if (kk == 0) rsum[r] = sm;
  }
  __syncthreads();
  float accv[4] = {};
  const float* tb = tt + (size_t)bh * NLM * HD;
  int d = tid & 63, g = tid >> 6;
  int r0 = g * 4;
  for (int jc = 0; jc < 2; ++jc) {
    __syncthreads();
    for (int u = 0; u < 32; ++u) {
      int e = u * 256 + tid;
      cb[e >> 6][e & 63] = tb[jc * 128 * 64 + e];
    }
    __syncthreads();
    for (int jl = 0; jl < 128; ++jl) {
      float vv = cb[jl][d];
#pragma unroll
      for (int rr = 0; rr < 4; ++rr)
        accv[rr] = fmaf(S[r0 + rr][jc * 128 + jl], vv, accv[rr]);
    }
  }
#pragma unroll
  for (int rr = 0; rr < 4; ++rr) {
    int i = i0 + r0 + rr;
    outp[((size_t)bb * SEQ + i) * DIMC + h * HD + d] = accv[rr] / rsum[r0 + rr];
  }
}

// ---------------------------------------------------------------------------
// K9: depthwise residual conv along seq, added into out_pre
// ---------------------------------------------------------------------------
__global__ void conv_add(const float* __restrict__ v, const float* __restrict__ kern,
                         float* __restrict__ outp) {
  int idx = blockIdx.x * 256 + threadIdx.x;
  int d = idx & 63;
  int n = (idx >> 6) & 4095;
  int bh = idx >> 18;
  int bb = bh >> 3, h = bh & 7;
  __shared__ float ks[KWIN];
  if (threadIdx.x < KWIN) ks[threadIdx.x] = kern[h * KWIN + threadIdx.x];
  __syncthreads();
  const float* vb = v + (size_t)bh * SEQ * HD;
  float s = 0.f;
#pragma unroll
  for (int t = 0; t < KWIN; ++t) {
    int nn = n + t - (KWIN / 2);
    if (nn >= 0 && nn < SEQ) s = fmaf(ks[t], vb[(size_t)nn * HD + d], s);
  }
  size_t o = ((size_t)bb * SEQ + n) * DIMC + h * HD + d;
  outp[o] += s;
}

// ---------------------------------------------------------------------------
// K10: d_out = out_pre @ Wout + bout
// ---------------------------------------------------------------------------
__global__ __launch_bounds__(256) void out_gemm(const float* __restrict__ Ain,
                                                const float* __restrict__ W,
                                                const float* __restrict__ bias,
                                                float* __restrict__ Cout) {
  __shared__ float As[16][65];
  __shared__ float Bs[16][64];
  const int tid = threadIdx.x;
  const int tx = tid & 15, ty = tid >> 4;
  const int row0 = blockIdx.x * 64;
  const int col0 = blockIdx.y * 64;
  float acc[4][4] = {};
  for (int k0 = 0; k0 < 512; k0 += 16) {
    {
      int i = tid >> 2, kk = (tid & 3) * 4;
      const float4 a = *(const float4*)&Ain[(size_t)(row0 + i) * 512 + k0 + kk];
      As[kk + 0][i] = a.x; As[kk + 1][i] = a.y; As[kk + 2][i] = a.z; As[kk + 3][i] = a.w;
    }
    {
      int kk = tid >> 4, c = (tid & 15) * 4;
      *(float4*)&Bs[kk][c] = *(const float4*)&W[(size_t)(k0 + kk) * 512 + col0 + c];
    }
    __syncthreads();
#pragma unroll
    for (int kk = 0; kk < 16; ++kk) {
      float a[4], b[4];
#pragma unroll
      for (int ii = 0; ii < 4; ++ii) a[ii] = As[kk][ty * 4 + ii];
#pragma unroll
      for (int jj = 0; jj < 4; ++jj) b[jj] = Bs[kk][tx * 4 + jj];
#pragma unroll
      for (int ii = 0; ii < 4; ++ii)
#pragma unroll
        for (int jj = 0; jj < 4; ++jj) acc[ii][jj] = fmaf(a[ii], b[jj], acc[ii][jj]);
    }
    __syncthreads();
  }
  const int cbase = col0 + tx * 4;
  const float4 bv = *(const float4*)&bias[cbase];
#pragma unroll
  for (int ii = 0; ii < 4; ++ii) {
    int rg = row0 + ty * 4 + ii;
    float4 o;
    o.x = acc[ii][0] + bv.x; o.y = acc[ii][1] + bv.y;
    o.z = acc[ii][2] + bv.z; o.w = acc[ii][3] + bv.w;
    *(float4*)&Cout[(size_t)rg * 512 + cbase] = o;
  }
}

// ---------------------------------------------------------------------------
extern "C" void kernel_launch(void* const* d_in, const int* in_sizes, int n_in,
                              void* d_out, int out_size, void* d_ws, size_t ws_size,
                              hipStream_t stream) {
  const float* x    = (const float*)d_in[0];
  const float* Wqkv = (const float*)d_in[1];
  const float* Wout = (const float*)d_in[2];
  const float* bout = (const float*)d_in[3];
  const float* rker = (const float*)d_in[4];
  float* out = (float*)d_out;
  float* ws = (float*)d_ws;

  // workspace layout (float element offsets) — same footprint as round 1
  float* q    = ws;                 // 8388608
  float* k    = ws + 8388608;       // 8388608
  float* v    = ws + 16777216;      // 8388608
  float* qlm  = ws + 25165824;      // 524288
  float* klm  = ws + 25690112;      // 524288
  float* a2   = ws + 26214400;      // 2097152
  float* za   = ws + 28311552;      // 2097152
  float* zb   = ws + 30408704;      // 2097152
  float* xz   = ws + 32505856;      // 2097152 (later: sim3 O_part)
  float* t2   = ws + 34603008;      // 2097152 (later: sim3 l_part)
  float* t3   = ws + 36700160;      // 2097152 (later: qlm_bf)
  float* sv   = ws + 38797312;      // 524288
  float* tt   = ws + 39321600;      // 524288
  float* outp = ws + 39845888;      // 8388608 (early: k_bf + vT_bf)
  float* red  = ws + 48234496;      // 128

  unsigned short* qlm_bf = (unsigned short*)t3;
  unsigned short* k_bf   = (unsigned short*)outp;               // 8388608 ushorts
  unsigned short* vT_bf  = (unsigned short*)(outp + 4194304);   // 8388608 ushorts
  float* O_part = xz;
  float* l_part = t2;

  qkv_gemm<<<dim3(256, 24), 256, 0, stream>>>(x, Wqkv, q, k, v);
  landmark_kernel<<<2048, 256, 0, stream>>>(q, qlm);
  landmark_kernel<<<2048, 256, 0, stream>>>(k, klm);
  sim2_softmax<<<8192, 256, 0, stream>>>(qlm, klm, a2);
  colrow_max<<<32, 256, 0, stream>>>(a2, red);
  finalize_scale<<<1, 64, 0, stream>>>(red);
  zinit<<<8192, 256, 0, stream>>>(a2, red, za);

  // pinv Newton-Schulz in split-bf16 MFMA (fp32-class accuracy)
  float* zc = za;
  float* zn = zb;
  for (int it = 0; it < 6; ++it) {
    bgemm_mfma3<<<dim3(4, 4, 32), 256, 0, stream>>>(a2, zc, a2, xz, 256, 256, 256, 0.f, -1.f);
    bgemm_mfma3<<<dim3(4, 4, 32), 256, 0, stream>>>(xz, xz, xz, t2, 256, 256, 256, 7.f, 1.f);
    bgemm_mfma3<<<dim3(4, 4, 32), 256, 0, stream>>>(xz, t2, xz, t3, 256, 256, 256, 15.f, 1.f);
    bgemm_mfma3<<<dim3(4, 4, 32), 256, 0, stream>>>(zc, t3, zc, zn, 256, 256, 256, 13.f, 0.25f);
    float* tp = zc; zc = zn; zn = tp;
  }
  // zc == za == attn2_inv; xz/t2/t3 now free for reuse

  // bf16 copies for sim3 (lifetimes: t3 & outp regions are free here)
  cvt_bf16_flat<<<512, 256, 0, stream>>>(qlm, qlm_bf, 131072);
  cvt_bf16_flat<<<8192, 256, 0, stream>>>(k, k_bf, 2097152);
  vT_cvt<<<dim3(64, 32), 256, 0, stream>>>(v, vT_bf);

  sim3_mfma<<<dim3(4, NCH, 32), 256, 0, stream>>>(qlm_bf, k_bf, vT_bf, O_part, l_part);
  sim3_finalize<<<2048, 256, 0, stream>>>(O_part, l_part, sv);

  // tt = attn2_inv @ sv  (alpha=0 -> E unused numerically; pass tt itself)
  bgemm_mfma3<<<dim3(4, 1, 32), 256, 0, stream>>>(zc, sv, tt, tt, 256, 64, 256, 0.f, -1.f);

  attn1_apply<<<dim3(256, 32), 256, 0, stream>>>(q, klm, tt, outp);
  conv_add<<<32768, 256, 0, stream>>>(v, rker, outp);
  out_gemm<<<dim3(256, 8), 256, 0, stream>>>(outp, Wout, bout, out);
}

// Round 5
// 1085.461 us; speedup vs baseline: 2.0165x; 1.4984x over previous
//
#include <hip/hip_runtime.h>
#include <math.h>

// Problem constants
constexpr int BATCH = 4;
constexpr int SEQ   = 4096;
constexpr int DIMC  = 512;
constexpr int NH    = 8;
constexpr int HD    = 64;
constexpr int NLM   = 256;   // landmarks M
constexpr int LWIN  = 16;    // SEQ / NLM
constexpr int KWIN  = 33;
constexpr int BH    = BATCH * NH; // 32

typedef __attribute__((ext_vector_type(8))) short  bfrag;  // 8 bf16 for MFMA A/B
typedef __attribute__((ext_vector_type(4))) float  ffrag;  // MFMA C/D
typedef __attribute__((ext_vector_type(8))) unsigned short us8;
typedef __attribute__((ext_vector_type(4))) unsigned short us4;
typedef unsigned short ush;

__device__ __forceinline__ ush f2bf(float f) {
  unsigned u = __builtin_bit_cast(unsigned, f);
  return (ush)((u + 0x7FFFu + ((u >> 16) & 1u)) >> 16);
}
__device__ __forceinline__ float bf2f(ush h) {
  unsigned u = ((unsigned)h) << 16;
  return __builtin_bit_cast(float, u);
}
__device__ __forceinline__ void splitf(float f, ush& h, ush& l) {
  h = f2bf(f);
  l = f2bf(f - bf2f(h));
}

// ---------------------------------------------------------------------------
// split_flat: fp32 -> (hi, lo) bf16, elementwise (x pre-split)
// ---------------------------------------------------------------------------
__global__ void split_flat(const float* __restrict__ src, ush* __restrict__ oh,
                           ush* __restrict__ ol, int n4) {
  int i = blockIdx.x * 256 + threadIdx.x;
  if (i >= n4) return;
  float4 f = ((const float4*)src)[i];
  us4 h, l;
  float fs[4] = {f.x, f.y, f.z, f.w};
#pragma unroll
  for (int j = 0; j < 4; ++j) {
    ush hh, ll;
    splitf(fs[j], hh, ll);
    h[j] = hh; l[j] = ll;
  }
  ((us4*)oh)[i] = h;
  ((us4*)ol)[i] = l;
}

// ---------------------------------------------------------------------------
// transpose_split_w: in [R][C] fp32 -> out [C][R] hi/lo bf16 (weights)
// grid (C/32, R/32), 256 threads
// ---------------------------------------------------------------------------
__global__ __launch_bounds__(256) void transpose_split_w(const float* __restrict__ in,
                                                         ush* __restrict__ oh,
                                                         ush* __restrict__ ol,
                                                         int R, int C) {
  __shared__ float T[32][33];
  const int tid = threadIdx.x;
  const int c0 = blockIdx.x * 32, r0 = blockIdx.y * 32;
#pragma unroll
  for (int u = 0; u < 4; ++u) {
    int r = (tid >> 5) * 4 + u, cl = tid & 31;
    T[r][cl] = in[(size_t)(r0 + r) * C + c0 + cl];
  }
  __syncthreads();
#pragma unroll
  for (int u = 0; u < 4; ++u) {
    int cl = (tid >> 5) * 4 + u, rl = tid & 31;
    float f = T[rl][cl];
    ush h, l; splitf(f, h, l);
    size_t o = (size_t)(c0 + cl) * R + r0 + rl;
    oh[o] = h; ol[o] = l;
  }
}

// ---------------------------------------------------------------------------
// K1: qkv split-bf16 MFMA GEMM. A = x split [16384][512], B = WqkvT split
// [1536][512]. BM=BN=128, BK=32, 256 thr (4 waves, each 64x64).
// Epilogue: q->q_bf (+0.125 scale, + qlm window sums), k->k_bf (+klm),
// v->v_bf. grid (128, 12).
// ---------------------------------------------------------------------------
__global__ __launch_bounds__(256) void qkv_mfma(const ush* __restrict__ xh,
                                                const ush* __restrict__ xl,
                                                const ush* __restrict__ wTh,
                                                const ush* __restrict__ wTl,
                                                ush* __restrict__ q_bf,
                                                ush* __restrict__ k_bf,
                                                ush* __restrict__ v_bf,
                                                float* __restrict__ qlm,
                                                float* __restrict__ klm) {
  __shared__ ush Ash[128][40], Asl[128][40];
  __shared__ ush Bsh[128][40], Bsl[128][40];
  const int tid = threadIdx.x;
  const int w = tid >> 6, lane = tid & 63;
  const int lm = lane & 15, lq = lane >> 4;
  const int wm = w >> 1, wn = w & 1;
  const int row0 = blockIdx.x * 128, col0 = blockIdx.y * 128;
  const ffrag fz = {0.f, 0.f, 0.f, 0.f};
  ffrag acc[4][4];
#pragma unroll
  for (int i = 0; i < 4; ++i)
#pragma unroll
    for (int j = 0; j < 4; ++j) acc[i][j] = fz;

  const int sm = tid >> 1, skoff = (tid & 1) * 16;
  for (int k0 = 0; k0 < 512; k0 += 32) {
    __syncthreads();
    {
      size_t ao = (size_t)(row0 + sm) * 512 + k0 + skoff;
      *(us8*)&Ash[sm][skoff]     = *(const us8*)&xh[ao];
      *(us8*)&Ash[sm][skoff + 8] = *(const us8*)&xh[ao + 8];
      *(us8*)&Asl[sm][skoff]     = *(const us8*)&xl[ao];
      *(us8*)&Asl[sm][skoff + 8] = *(const us8*)&xl[ao + 8];
      size_t bo = (size_t)(col0 + sm) * 512 + k0 + skoff;
      *(us8*)&Bsh[sm][skoff]     = *(const us8*)&wTh[bo];
      *(us8*)&Bsh[sm][skoff + 8] = *(const us8*)&wTh[bo + 8];
      *(us8*)&Bsl[sm][skoff]     = *(const us8*)&wTl[bo];
      *(us8*)&Bsl[sm][skoff + 8] = *(const us8*)&wTl[bo + 8];
    }
    __syncthreads();
    bfrag ah[4], al[4], bh[4], bl[4];
#pragma unroll
    for (int mt = 0; mt < 4; ++mt) {
      ah[mt] = *(const bfrag*)&Ash[64 * wm + 16 * mt + lm][8 * lq];
      al[mt] = *(const bfrag*)&Asl[64 * wm + 16 * mt + lm][8 * lq];
    }
#pragma unroll
    for (int nt = 0; nt < 4; ++nt) {
      bh[nt] = *(const bfrag*)&Bsh[64 * wn + 16 * nt + lm][8 * lq];
      bl[nt] = *(const bfrag*)&Bsl[64 * wn + 16 * nt + lm][8 * lq];
    }
#pragma unroll
    for (int mt = 0; mt < 4; ++mt)
#pragma unroll
      for (int nt = 0; nt < 4; ++nt) {
        acc[mt][nt] = __builtin_amdgcn_mfma_f32_16x16x32_bf16(ah[mt], bh[nt], acc[mt][nt], 0, 0, 0);
        acc[mt][nt] = __builtin_amdgcn_mfma_f32_16x16x32_bf16(al[mt], bh[nt], acc[mt][nt], 0, 0, 0);
        acc[mt][nt] = __builtin_amdgcn_mfma_f32_16x16x32_bf16(ah[mt], bl[nt], acc[mt][nt], 0, 0, 0);
      }
  }
  // epilogue
#pragma unroll
  for (int mt = 0; mt < 4; ++mt) {
    int rbase = row0 + 64 * wm + 16 * mt;      // 16-aligned -> single window
    int b = rbase >> 12;
    int ntok_base = rbase & 4095;
    int win = ntok_base >> 4;
#pragma unroll
    for (int nt = 0; nt < 4; ++nt) {
      int n_local = 64 * wn + 16 * nt;          // frag col base (h uniform)
      int col = col0 + n_local + lm;
      int which = col >> 9;                     // 0=q 1=k 2=v
      int h = (col >> 6) & 7;
      int d = col & 63;
      int bh_i = b * NH + h;
      float scale = (which == 0) ? 0.125f : 1.0f;
      float vals[4];
      float s = 0.f;
#pragma unroll
      for (int r = 0; r < 4; ++r) {
        vals[r] = acc[mt][nt][r] * scale;
        s += vals[r];
      }
      // write bf16 element copies
      ush* dst = which == 0 ? q_bf : (which == 1 ? k_bf : v_bf);
#pragma unroll
      for (int r = 0; r < 4; ++r) {
        int ntok = ntok_base + 4 * lq + r;
        dst[((size_t)bh_i * SEQ + ntok) * HD + d] = f2bf(vals[r]);
      }
      if (which < 2) {
        // window sum over 16 rows: r-sum + reduce across lq (lane bits 4,5)
        s += __shfl_xor(s, 16);
        s += __shfl_xor(s, 32);
        if (lq == 0) {
          float* lmdst = which == 0 ? qlm : klm;
          lmdst[((size_t)bh_i * NLM + win) * HD + d] = s * (1.0f / LWIN);
        }
      }
    }
  }
}

// ---------------------------------------------------------------------------
// K3: attn2 = softmax(qlm @ klm^T) rows -> split bf16 (a2h/a2l)
// ---------------------------------------------------------------------------
__global__ __launch_bounds__(256) void sim2_softmax(const float* __restrict__ qlm,
                                                    const float* __restrict__ klm,
                                                    ush* __restrict__ a2h,
                                                    ush* __restrict__ a2l) {
  int i = blockIdx.x & 255;
  int bh = blockIdx.x >> 8;
  int j = threadIdx.x;
  __shared__ float qrow[64];
  __shared__ float red[256];
  if (j < 64) qrow[j] = qlm[((size_t)bh * NLM + i) * HD + j];
  __syncthreads();
  const float* kr = klm + ((size_t)bh * NLM + j) * HD;
  float s = 0.f;
#pragma unroll
  for (int d = 0; d < 64; d += 4) {
    float4 kv = *(const float4*)&kr[d];
    s += qrow[d] * kv.x + qrow[d + 1] * kv.y + qrow[d + 2] * kv.z + qrow[d + 3] * kv.w;
  }
  red[j] = s; __syncthreads();
  for (int off = 128; off > 0; off >>= 1) {
    if (j < off) red[j] = fmaxf(red[j], red[j + off]);
    __syncthreads();
  }
  float mx = red[0]; __syncthreads();
  float e = expf(s - mx);
  red[j] = e; __syncthreads();
  for (int off = 128; off > 0; off >>= 1) {
    if (j < off) red[j] += red[j + off];
    __syncthreads();
  }
  float val = e / red[0];
  size_t o = ((size_t)bh * NLM + i) * NLM + j;
  ush h, l; splitf(val, h, l);
  a2h[o] = h; a2l[o] = l;
}

// ---------------------------------------------------------------------------
// K4a: per-bh column/row sums of attn2, block-max of each
// ---------------------------------------------------------------------------
__global__ __launch_bounds__(256) void colrow_max(const ush* __restrict__ a2h,
                                                  const ush* __restrict__ a2l,
                                                  float* __restrict__ red) {
  int bh = blockIdx.x;
  int t = threadIdx.x;
  const size_t base = (size_t)bh * NLM * NLM;
  float cs = 0.f, rs = 0.f;
  for (int i = 0; i < NLM; ++i) {
    size_t o = base + (size_t)i * NLM + t;
    cs += bf2f(a2h[o]) + bf2f(a2l[o]);
  }
  for (int j = 0; j < NLM; ++j) {
    size_t o = base + (size_t)t * NLM + j;
    rs += bf2f(a2h[o]) + bf2f(a2l[o]);
  }
  __shared__ float r1[256], r2[256];
  r1[t] = cs; r2[t] = rs; __syncthreads();
  for (int off = 128; off > 0; off >>= 1) {
    if (t < off) { r1[t] = fmaxf(r1[t], r1[t + off]); r2[t] = fmaxf(r2[t], r2[t + off]); }
    __syncthreads();
  }
  if (t == 0) { red[bh] = r1[0]; red[32 + bh] = r2[0]; }
}

__global__ void finalize_scale(float* __restrict__ red) {
  if (threadIdx.x == 0) {
    float m1 = -1e30f, m2 = -1e30f;
    for (int i = 0; i < BH; ++i) { m1 = fmaxf(m1, red[i]); m2 = fmaxf(m2, red[32 + i]); }
    red[64] = 1.0f / (m1 * m2);
  }
}

// ---------------------------------------------------------------------------
// K4c: z0 = attn2^T * invscale, emitted in A-form ([i][j], transposed) and
// B-form ([j][i] == scaled a2, natural). grid (8, 8, 32), 256 thr, 32x32 tiles
// ---------------------------------------------------------------------------
__global__ __launch_bounds__(256) void zinit_split(const ush* __restrict__ a2h,
                                                   const ush* __restrict__ a2l,
                                                   const float* __restrict__ red,
                                                   ush* __restrict__ zAh, ush* __restrict__ zAl,
                                                   ush* __restrict__ zBh, ush* __restrict__ zBl) {
  __shared__ float T[32][33];
  const int tid = threadIdx.x;
  const int bh = blockIdx.z;
  const int j0 = blockIdx.x * 32, i0 = blockIdx.y * 32;
  const float s = red[64];
  const size_t base = (size_t)bh * NLM * NLM;
#pragma unroll
  for (int u = 0; u < 4; ++u) {
    int jl = (tid >> 5) * 4 + u, il = tid & 31;
    size_t o = base + (size_t)(j0 + jl) * NLM + i0 + il;
    float a = (bf2f(a2h[o]) + bf2f(a2l[o])) * s;
    T[jl][il] = a;
    ush h, l; splitf(a, h, l);
    zBh[o] = h; zBl[o] = l;   // zB[j][i] = a2[j][i]*s
  }
  __syncthreads();
#pragma unroll
  for (int u = 0; u < 4; ++u) {
    int il = (tid >> 5) * 4 + u, jl = tid & 31;
    float a = T[jl][il];
    ush h, l; splitf(a, h, l);
    size_t o = base + (size_t)(i0 + il) * NLM + j0 + jl;  // zA[i][j] = a2[j][i]*s
    zAh[o] = h; zAl[o] = l;
  }
}

// ---------------------------------------------------------------------------
// K5: pinv workhorse. Pure-bf16-read split GEMM:
//   C = A@B (split 3-product), Y = coef*(alpha*(Eh+El) - C)
// A-form inputs [m][K], B-form inputs [n][K]. Outputs (optional): A-form
// split [M][N], B-form split [N][M]. BM=128, BN=64, BK=32; 256 thr;
// 4 waves each 64x32. grid (M/128, N/64, 32).
// ---------------------------------------------------------------------------
__global__ __launch_bounds__(256) void bgemm_split(
    const ush* __restrict__ Ah, const ush* __restrict__ Al,
    const ush* __restrict__ Bh, const ush* __restrict__ Bl,
    const ush* __restrict__ Eh, const ush* __restrict__ El,
    ush* oAh, ush* oAl, ush* oBh, ush* oBl,
    int M, int N, int K, float alpha, float coef) {
  __shared__ ush Ash[128][40], Asl[128][40];
  __shared__ ush Bsh[64][40], Bsl[64][40];
  const int batch = blockIdx.z;
  const size_t abase = (size_t)batch * M * K;
  const size_t bbase = (size_t)batch * N * K;
  const size_t ebase = (size_t)batch * M * N;
  const int tid = threadIdx.x;
  const int w = tid >> 6, lane = tid & 63;
  const int lm = lane & 15, lq = lane >> 4;
  const int wm = w >> 1, wn = w & 1;
  const int row0 = blockIdx.x * 128, col0 = blockIdx.y * 64;
  const ffrag fz = {0.f, 0.f, 0.f, 0.f};
  ffrag acc[4][2];
#pragma unroll
  for (int i = 0; i < 4; ++i) { acc[i][0] = fz; acc[i][1] = fz; }

  const int am = tid >> 1, akoff = (tid & 1) * 16;   // A stage: 128x32
  const int bn = tid >> 2, bkoff = (tid & 3) * 8;    // B stage: 64x32
  for (int k0 = 0; k0 < K; k0 += 32) {
    __syncthreads();
    {
      size_t ao = abase + (size_t)(row0 + am) * K + k0 + akoff;
      *(us8*)&Ash[am][akoff]     = *(const us8*)&Ah[ao];
      *(us8*)&Ash[am][akoff + 8] = *(const us8*)&Ah[ao + 8];
      *(us8*)&Asl[am][akoff]     = *(const us8*)&Al[ao];
      *(us8*)&Asl[am][akoff + 8] = *(const us8*)&Al[ao + 8];
      size_t bo = bbase + (size_t)(col0 + bn) * K + k0 + bkoff;
      *(us8*)&Bsh[bn][bkoff] = *(const us8*)&Bh[bo];
      *(us8*)&Bsl[bn][bkoff] = *(const us8*)&Bl[bo];
    }
    __syncthreads();
    bfrag ah[4], al[4], bhf[2], blf[2];
#pragma unroll
    for (int mt = 0; mt < 4; ++mt) {
      ah[mt] = *(const bfrag*)&Ash[64 * wm + 16 * mt + lm][8 * lq];
      al[mt] = *(const bfrag*)&Asl[64 * wm + 16 * mt + lm][8 * lq];
    }
#pragma unroll
    for (int nt = 0; nt < 2; ++nt) {
      bhf[nt] = *(const bfrag*)&Bsh[32 * wn + 16 * nt + lm][8 * lq];
      blf[nt] = *(const bfrag*)&Bsl[32 * wn + 16 * nt + lm][8 * lq];
    }
#pragma unroll
    for (int mt = 0; mt < 4; ++mt)
#pragma unroll
      for (int nt = 0; nt < 2; ++nt) {
        acc[mt][nt] = __builtin_amdgcn_mfma_f32_16x16x32_bf16(ah[mt], bhf[nt], acc[mt][nt], 0, 0, 0);
        acc[mt][nt] = __builtin_amdgcn_mfma_f32_16x16x32_bf16(al[mt], bhf[nt], acc[mt][nt], 0, 0, 0);
        acc[mt][nt] = __builtin_amdgcn_mfma_f32_16x16x32_bf16(ah[mt], blf[nt], acc[mt][nt], 0, 0, 0);
      }
  }
#pragma unroll
  for (int mt = 0; mt < 4; ++mt)
#pragma unroll
    for (int nt = 0; nt < 2; ++nt) {
      int n = col0 + 32 * wn + 16 * nt + lm;
#pragma unroll
      for (int r = 0; r < 4; ++r) {
        int m = row0 + 64 * wm + 16 * mt + 4 * lq + r;
        float c = acc[mt][nt][r];
        float y;
        if (Eh) {
          size_t eo = ebase + (size_t)m * N + n;
          float e = bf2f(Eh[eo]) + bf2f(El[eo]);
          y = coef * (alpha * e - c);
        } else {
          y = -coef * c;
        }
        ush h, l; splitf(y, h, l);
        if (oAh) {
          size_t o = ebase + (size_t)m * N + n;
          oAh[o] = h; oAl[o] = l;
        }
        if (oBh) {
          size_t o = (size_t)batch * N * M + (size_t)n * M + m;
          oBh[o] = h;
          if (oBl) oBl[o] = l;
        }
      }
    }
}

// ---------------------------------------------------------------------------
// vT_cvt_bf: v_bf [bh][n][d] -> vT_bf [bh][d][n]. grid (64, 32)
// ---------------------------------------------------------------------------
__global__ __launch_bounds__(256) void vT_cvt_bf(const ush* __restrict__ v_bf,
                                                 ush* __restrict__ vT) {
  __shared__ ush T[64][72];
  const int bh = blockIdx.y;
  const int n0 = blockIdx.x * 64;
  const int tid = threadIdx.x;
  {
    int n = tid >> 2, off = (tid & 3) * 16;
    const ush* src = &v_bf[((size_t)bh * SEQ + n0 + n) * HD + off];
    *(us8*)&T[n][off] = *(const us8*)src;
    *(us8*)&T[n][off + 8] = *(const us8*)&src[8];
  }
  __syncthreads();
  {
    int d = tid >> 2, noff = (tid & 3) * 16;
    us8 o0, o1;
#pragma unroll
    for (int j = 0; j < 8; ++j) o0[j] = T[noff + j][d];
#pragma unroll
    for (int j = 0; j < 8; ++j) o1[j] = T[noff + 8 + j][d];
    ush* dst = &vT[((size_t)bh * HD + d) * SEQ + n0 + noff];
    *(us8*)dst = o0;
    *(us8*)&dst[8] = o1;
  }
}

// ---------------------------------------------------------------------------
// K6: sim3 flash via MFMA, no max-subtraction (scores tiny). n-split NCH ways.
// ---------------------------------------------------------------------------
constexpr int NCH = 4;
__global__ __launch_bounds__(256) void sim3_mfma(const float* __restrict__ qlm,
                                                 const ush* __restrict__ k_bf,
                                                 const ush* __restrict__ vT_bf,
                                                 float* __restrict__ O_part,
                                                 float* __restrict__ l_part) {
  constexpr int CHUNK = SEQ / NCH;  // 1024
  __shared__ ush Qs[64][72];
  __shared__ ush Ks[128][72];
  __shared__ ush Vs[64][136];
  __shared__ ush Ps[64][136];
  const int bh = blockIdx.z;
  const int m0 = blockIdx.x * 64;
  const int n_base = blockIdx.y * CHUNK;
  const int tid = threadIdx.x;
  const int w = tid >> 6, lane = tid & 63;
  const int lm = lane & 15, lq = lane >> 4;
  {
    int m = tid >> 2, off = (tid & 3) * 16;
    const float* src = &qlm[((size_t)bh * NLM + m0 + m) * HD + off];
    us8 o0, o1;
#pragma unroll
    for (int j = 0; j < 8; ++j) o0[j] = f2bf(src[j]);
#pragma unroll
    for (int j = 0; j < 8; ++j) o1[j] = f2bf(src[8 + j]);
    *(us8*)&Qs[m][off] = o0;
    *(us8*)&Qs[m][off + 8] = o1;
  }
  const ffrag fz = {0.f, 0.f, 0.f, 0.f};
  ffrag O[4] = {fz, fz, fz, fz};
  float lsum[4] = {0.f, 0.f, 0.f, 0.f};

  for (int n0 = 0; n0 < CHUNK; n0 += 128) {
    __syncthreads();
    {
      int n = tid >> 1, off = (tid & 1) * 32;
      const ush* src = &k_bf[((size_t)bh * SEQ + n_base + n0 + n) * HD + off];
#pragma unroll
      for (int u = 0; u < 4; ++u) *(us8*)&Ks[n][off + 8 * u] = *(const us8*)&src[8 * u];
    }
    {
      int d = tid >> 2, off = (tid & 3) * 32;
      const ush* src = &vT_bf[((size_t)bh * HD + d) * SEQ + n_base + n0 + off];
#pragma unroll
      for (int u = 0; u < 4; ++u) *(us8*)&Vs[d][off + 8 * u] = *(const us8*)&src[8 * u];
    }
    __syncthreads();
    ffrag S[8] = {fz, fz, fz, fz, fz, fz, fz, fz};
#pragma unroll
    for (int ks = 0; ks < 2; ++ks) {
      bfrag a = *(const bfrag*)&Qs[16 * w + lm][32 * ks + 8 * lq];
#pragma unroll
      for (int t = 0; t < 8; ++t) {
        bfrag b = *(const bfrag*)&Ks[16 * t + lm][32 * ks + 8 * lq];
        S[t] = __builtin_amdgcn_mfma_f32_16x16x32_bf16(a, b, S[t], 0, 0, 0);
      }
    }
#pragma unroll
    for (int t = 0; t < 8; ++t)
#pragma unroll
      for (int r = 0; r < 4; ++r) {
        float p = __expf(S[t][r]);
        lsum[r] += p;
        Ps[16 * w + 4 * lq + r][16 * t + lm] = f2bf(p);
      }
    __syncthreads();
#pragma unroll
    for (int kk = 0; kk < 4; ++kk) {
      bfrag a = *(const bfrag*)&Ps[16 * w + lm][32 * kk + 8 * lq];
#pragma unroll
      for (int t2 = 0; t2 < 4; ++t2) {
        bfrag b = *(const bfrag*)&Vs[16 * t2 + lm][32 * kk + 8 * lq];
        O[t2] = __builtin_amdgcn_mfma_f32_16x16x32_bf16(a, b, O[t2], 0, 0, 0);
      }
    }
  }
#pragma unroll
  for (int r = 0; r < 4; ++r) {
#pragma unroll
    for (int off = 1; off < 16; off <<= 1) lsum[r] += __shfl_xor(lsum[r], off);
  }
  const size_t pbase = (size_t)blockIdx.y * 32 + bh;
  if (lm == 0) {
#pragma unroll
    for (int r = 0; r < 4; ++r)
      l_part[pbase * NLM + m0 + 16 * w + 4 * lq + r] = lsum[r];
  }
#pragma unroll
  for (int t2 = 0; t2 < 4; ++t2)
#pragma unroll
    for (int r = 0; r < 4; ++r) {
      int m = m0 + 16 * w + 4 * lq + r;
      int d = 16 * t2 + lm;
      O_part[(pbase * NLM + m) * HD + d] = O[t2][r];
    }
}

// sim3_finalize: combine partials, write sv in B-form split ([d][m]).
// grid (32), 256 threads, one block per bh.
__global__ __launch_bounds__(256) void sim3_finalize(const float* __restrict__ O_part,
                                                     const float* __restrict__ l_part,
                                                     ush* __restrict__ svBh,
                                                     ush* __restrict__ svBl) {
  __shared__ float acc[256 * 65];
  __shared__ float ls[256];
  const int bh = blockIdx.x;
  const int tid = threadIdx.x;
  for (int e = tid; e < 16384; e += 256) {
    float s = 0.f;
#pragma unroll
    for (int c = 0; c < NCH; ++c) s += O_part[(((size_t)(c * 32 + bh)) << 14) + e];
    acc[(e >> 6) * 65 + (e & 63)] = s;
  }
  {
    float s = 0.f;
#pragma unroll
    for (int c = 0; c < NCH; ++c) s += l_part[(size_t)(c * 32 + bh) * NLM + tid];
    ls[tid] = s;
  }
  __syncthreads();
  for (int e = tid; e < 16384; e += 256) {
    int d = e >> 8, m = e & 255;
    float val = acc[m * 65 + d] / ls[m];
    ush h, l; splitf(val, h, l);
    size_t o = ((size_t)bh * HD + d) * NLM + m;
    svBh[o] = h; svBl[o] = l;
  }
}

// ---------------------------------------------------------------------------
// K8: attn1 via MFMA: outp = softmax(q_bf @ klm^T) @ tt  (fp32 softmax)
// grid (64, 32), 256 thr. Block: 64 q-rows, full 256 landmarks.
// ---------------------------------------------------------------------------
__global__ __launch_bounds__(256) void attn1_mfma(const ush* __restrict__ q_bf,
                                                  const float* __restrict__ klm,
                                                  const ush* __restrict__ ttT,
                                                  float* __restrict__ outp) {
  __shared__ ush bufA[256 * 72];   // klm bf16 [256][72] then ttT [64][264]
  __shared__ ush bufB[64 * 264];   // qs [64][72] then Ps [64][264]
  const int bh = blockIdx.y;
  const int b = bh >> 3, h = bh & 7;
  const int i0 = blockIdx.x * 64;
  const int tid = threadIdx.x;
  const int w = tid >> 6, lane = tid & 63;
  const int lm = lane & 15, lq = lane >> 4;
  // stage qs (q_bf rows i0..i0+63) into bufB as [64][72]
  {
    int m = tid >> 2, off = (tid & 3) * 16;
    const ush* src = &q_bf[((size_t)bh * SEQ + i0 + m) * HD + off];
    *(us8*)&bufB[m * 72 + off] = *(const us8*)src;
    *(us8*)&bufB[m * 72 + off + 8] = *(const us8*)&src[8];
  }
  // stage klm (fp32 -> bf16) into bufA as [256][72]
  {
    const float* kb = klm + (size_t)bh * NLM * HD;
#pragma unroll
    for (int u = 0; u < 16; ++u) {
      int e4 = u * 256 + tid;           // float4 index, 4096 total
      float4 f = ((const float4*)kb)[e4];
      int row = e4 >> 4, col = (e4 & 15) * 4;
      ush* p = &bufA[row * 72 + col];
      p[0] = f2bf(f.x); p[1] = f2bf(f.y); p[2] = f2bf(f.z); p[3] = f2bf(f.w);
    }
  }
  __syncthreads();
  // phase 1: S = q @ klm^T  (wave w owns rows 16w..16w+15)
  const ffrag fz = {0.f, 0.f, 0.f, 0.f};
  ffrag S[16];
#pragma unroll
  for (int t = 0; t < 16; ++t) S[t] = fz;
#pragma unroll
  for (int ks = 0; ks < 2; ++ks) {
    bfrag a = *(const bfrag*)&bufB[(16 * w + lm) * 72 + 32 * ks + 8 * lq];
#pragma unroll
    for (int t = 0; t < 16; ++t) {
      bfrag bb = *(const bfrag*)&bufA[(16 * t + lm) * 72 + 32 * ks + 8 * lq];
      S[t] = __builtin_amdgcn_mfma_f32_16x16x32_bf16(a, bb, S[t], 0, 0, 0);
    }
  }
  // softmax over 256 cols per row (rows 4lq+r within wave strip)
  float rinv[4];
  float ev[16][4];
#pragma unroll
  for (int r = 0; r < 4; ++r) {
    float mx = -INFINITY;
#pragma unroll
    for (int t = 0; t < 16; ++t) mx = fmaxf(mx, S[t][r]);
#pragma unroll
    for (int off = 1; off < 16; off <<= 1) mx = fmaxf(mx, __shfl_xor(mx, off));
    float sm = 0.f;
#pragma unroll
    for (int t = 0; t < 16; ++t) { ev[t][r] = __expf(S[t][r] - mx); sm += ev[t][r]; }
#pragma unroll
    for (int off = 1; off < 16; off <<= 1) sm += __shfl_xor(sm, off);
    rinv[r] = 1.0f / sm;
  }
  __syncthreads();   // qs + klm reads done everywhere
  // write P (bf16) into bufB as [64][264]; stage ttT into bufA as [64][264]
#pragma unroll
  for (int t = 0; t < 16; ++t)
#pragma unroll
    for (int r = 0; r < 4; ++r)
      bufB[(16 * w + 4 * lq + r) * 264 + 16 * t + lm] = f2bf(ev[t][r]);
  {
    const ush* tb = ttT + (size_t)bh * HD * NLM;
#pragma unroll
    for (int u = 0; u < 8; ++u) {
      int e8 = u * 256 + tid;           // us8 index, 2048 total
      int row = e8 >> 5, col = (e8 & 31) * 8;
      *(us8*)&bufA[row * 264 + col] = *(const us8*)&tb[row * NLM + col];
    }
  }
  __syncthreads();
  // phase 2: O = P @ tt   (A = Ps rows 16w.., B = ttT rows = d)
  ffrag O[4] = {fz, fz, fz, fz};
#pragma unroll
  for (int kk = 0; kk < 8; ++kk) {
    bfrag a = *(const bfrag*)&bufB[(16 * w + lm) * 264 + 32 * kk + 8 * lq];
#pragma unroll
    for (int t2 = 0; t2 < 4; ++t2) {
      bfrag bb = *(const bfrag*)&bufA[(16 * t2 + lm) * 264 + 32 * kk + 8 * lq];
      O[t2] = __builtin_amdgcn_mfma_f32_16x16x32_bf16(a, bb, O[t2], 0, 0, 0);
    }
  }
#pragma unroll
  for (int t2 = 0; t2 < 4; ++t2)
#pragma unroll
    for (int r = 0; r < 4; ++r) {
      int i = i0 + 16 * w + 4 * lq + r;
      int d = 16 * t2 + lm;
      outp[((size_t)b * SEQ + i) * DIMC + h * HD + d] = O[t2][r] * rinv[r];
    }
}

// ---------------------------------------------------------------------------
// K9: conv add + split: outp(fp32) + depthwise conv(vT_bf) -> outph/outpl
// grid (64, 32): block = 64 seq positions x 64 dims for one bh
// ---------------------------------------------------------------------------
__global__ __launch_bounds__(256) void conv_add_split(const float* __restrict__ outp,
                                                      const ush* __restrict__ vT,
                                                      const float* __restrict__ kern,
                                                      ush* __restrict__ oh,
                                                      ush* __restrict__ ol) {
  __shared__ float vt[64 * 97];   // [d][96+1], cols n0-16 .. n0+79
  __shared__ float ks[KWIN];
  const int bh = blockIdx.y;
  const int b = bh >> 3, hh = bh & 7;
  const int n0 = blockIdx.x * 64;
  const int tid = threadIdx.x;
  if (tid < KWIN) ks[tid] = kern[hh * KWIN + tid];
  for (int e = tid; e < 64 * 96; e += 256) {
    int d = e / 96, c = e % 96;
    int n = n0 - 16 + c;
    vt[d * 97 + c] = (n >= 0 && n < SEQ) ? bf2f(vT[((size_t)bh * HD + d) * SEQ + n]) : 0.f;
  }
  __syncthreads();
  const int d = tid & 63, g = tid >> 6;
  float wreg[48];
#pragma unroll
  for (int j = 0; j < 48; ++j) wreg[j] = vt[d * 97 + g * 16 + j];
#pragma unroll
  for (int nn = 0; nn < 16; ++nn) {
    float s = 0.f;
#pragma unroll
    for (int t = 0; t < KWIN; ++t) s = fmaf(ks[t], wreg[nn + t], s);
    int n = n0 + g * 16 + nn;
    size_t o = ((size_t)b * SEQ + n) * DIMC + hh * HD + d;
    float val = outp[o] + s;
    ush h, l; splitf(val, h, l);
    oh[o] = h; ol[o] = l;
  }
}

// ---------------------------------------------------------------------------
// K10: out = outp_split @ WoutT_split + bias. BM=BN=128, grid (128, 4)
// ---------------------------------------------------------------------------
__global__ __launch_bounds__(256) void out_gemm_split(const ush* __restrict__ ah_g,
                                                      const ush* __restrict__ al_g,
                                                      const ush* __restrict__ bh_g,
                                                      const ush* __restrict__ bl_g,
                                                      const float* __restrict__ bias,
                                                      float* __restrict__ out) {
  __shared__ ush Ash[128][40], Asl[128][40];
  __shared__ ush Bsh[128][40], Bsl[128][40];
  const int tid = threadIdx.x;
  const int w = tid >> 6, lane = tid & 63;
  const int lm = lane & 15, lq = lane >> 4;
  const int wm = w >> 1, wn = w & 1;
  const int row0 = blockIdx.x * 128, col0 = blockIdx.y * 128;
  const ffrag fz = {0.f, 0.f, 0.f, 0.f};
  ffrag acc[4][4];
#pragma unroll
  for (int i = 0; i < 4; ++i)
#pragma unroll
    for (int j = 0; j < 4; ++j) acc[i][j] = fz;

  const int sm = tid >> 1, skoff = (tid & 1) * 16;
  for (int k0 = 0; k0 < 512; k0 += 32) {
    __syncthreads();
    {
      size_t ao = (size_t)(row0 + sm) * 512 + k0 + skoff;
      *(us8*)&Ash[sm][skoff]     = *(const us8*)&ah_g[ao];
      *(us8*)&Ash[sm][skoff + 8] = *(const us8*)&ah_g[ao + 8];
      *(us8*)&Asl[sm][skoff]     = *(const us8*)&al_g[ao];
      *(us8*)&Asl[sm][skoff + 8] = *(const us8*)&al_g[ao + 8];
      size_t bo = (size_t)(col0 + sm) * 512 + k0 + skoff;
      *(us8*)&Bsh[sm][skoff]     = *(const us8*)&bh_g[bo];
      *(us8*)&Bsh[sm][skoff + 8] = *(const us8*)&bh_g[bo + 8];
      *(us8*)&Bsl[sm][skoff]     = *(const us8*)&bl_g[bo];
      *(us8*)&Bsl[sm][skoff + 8] = *(const us8*)&bl_g[bo + 8];
    }
    __syncthreads();
    bfrag ah[4], al[4], bh[4], bl[4];
#pragma unroll
    for (int mt = 0; mt < 4; ++mt) {
      ah[mt] = *(const bfrag*)&Ash[64 * wm + 16 * mt + lm][8 * lq];
      al[mt] = *(const bfrag*)&Asl[64 * wm + 16 * mt + lm][8 * lq];
    }
#pragma unroll
    for (int nt = 0; nt < 4; ++nt) {
      bh[nt] = *(const bfrag*)&Bsh[64 * wn + 16 * nt + lm][8 * lq];
      bl[nt] = *(const bfrag*)&Bsl[64 * wn + 16 * nt + lm][8 * lq];
    }
#pragma unroll
    for (int mt = 0; mt < 4; ++mt)
#pragma unroll
      for (int nt = 0; nt < 4; ++nt) {
        acc[mt][nt] = __builtin_amdgcn_mfma_f32_16x16x32_bf16(ah[mt], bh[nt], acc[mt][nt], 0, 0, 0);
        acc[mt][nt] = __builtin_amdgcn_mfma_f32_16x16x32_bf16(al[mt], bh[nt], acc[mt][nt], 0, 0, 0);
        acc[mt][nt] = __builtin_amdgcn_mfma_f32_16x16x32_bf16(ah[mt], bl[nt], acc[mt][nt], 0, 0, 0);
      }
  }
#pragma unroll
  for (int mt = 0; mt < 4; ++mt)
#pragma unroll
    for (int nt = 0; nt < 4; ++nt) {
      int n = col0 + 64 * wn + 16 * nt + lm;
      float bv = bias[n];
#pragma unroll
      for (int r = 0; r < 4; ++r) {
        int m = row0 + 64 * wm + 16 * mt + 4 * lq + r;
        out[(size_t)m * 512 + n] = acc[mt][nt][r] + bv;
      }
    }
}

// ---------------------------------------------------------------------------
extern "C" void kernel_launch(void* const* d_in, const int* in_sizes, int n_in,
                              void* d_out, int out_size, void* d_ws, size_t ws_size,
                              hipStream_t stream) {
  const float* x    = (const float*)d_in[0];
  const float* Wqkv = (const float*)d_in[1];
  const float* Wout = (const float*)d_in[2];
  const float* bout = (const float*)d_in[3];
  const float* rker = (const float*)d_in[4];
  float* out = (float*)d_out;
  float* ws = (float*)d_ws;

  // workspace layout (float-element offsets), total ~186.6 MB
  ush*   v_bf   = (ush*)(ws);                          // 8388608 ush (4194304 f)
  ush*   q_bf   = (ush*)(ws + 4194304);                // 8388608 ush
  float* regA   = ws + 8388608;                        // 8388608 f: k_bf -> outp
  float* regB   = ws + 16777216;                       // 8388608 f: xh+xl -> outph+outpl
  float* qlm    = ws + 25165824;                       // 524288
  float* klm    = ws + 25690112;                       // 524288
  float* regC   = ws + 26214400;                       // 2097152 f: t2B(h,l) / ttT
  float* a2reg  = ws + 28311552;                       // 2097152 f: a2h+a2l
  float* zAreg  = ws + 30408704;                       // 4194304 f
  float* zBreg  = ws + 34603008;                       // 4194304 f (later vT_bf)
  float* xzreg  = ws + 38797312;                       // 4194304 f (later O_part/l_part)
  float* t3reg  = ws + 43515904;                       // 2097152 f (later svB)
  float* wqkvT  = ws + 45613056;                       // 786432 f
  float* woutT  = ws + 46399488;                       // 262144 f
  float* red    = ws + 46661632;                       // 128

  ush* k_bf  = (ush*)regA;
  float* outp = regA;
  // FIX (round 4): xh occupies 4194304 floats of regB; xl must start AFTER it
  // (round-3 bug: xl at regB+2097152 overlapped xh's second half -> garbage qkv)
  ush* xh = (ush*)regB;                 // 8388608 ush = [regB, regB+4194304f)
  ush* xl = (ush*)(regB + 4194304);     // 8388608 ush = [regB+4194304f, +8388608f)
  ush* outph = (ush*)regB;
  ush* outpl = (ush*)(regB + 4194304);
  ush* a2h = (ush*)a2reg;               // 2097152 ush each
  ush* a2l = (ush*)(a2reg + 1048576);
  // z buffers: 4 arrays of 2097152 ush each (Ah, Al, Bh, Bl)
  ush* zA_[4] = {(ush*)zAreg, (ush*)(zAreg + 1048576), (ush*)(zAreg + 2097152), (ush*)(zAreg + 3145728)};
  ush* zB_[4] = {(ush*)zBreg, (ush*)(zBreg + 1048576), (ush*)(zBreg + 2097152), (ush*)(zBreg + 3145728)};
  ush* xzA_h = (ush*)xzreg;             // xz A-form + B-form
  ush* xzA_l = (ush*)(xzreg + 1048576);
  ush* xzB_h = (ush*)(xzreg + 2097152);
  ush* xzB_l = (ush*)(xzreg + 3145728);
  ush* t2B_h = (ush*)regC;
  ush* t2B_l = (ush*)(regC + 1048576);
  ush* t3B_h = (ush*)t3reg;
  ush* t3B_l = (ush*)(t3reg + 1048576);
  ush* vT_bf = (ush*)zBreg;             // after pinv
  float* O_part = xzreg;                // after pinv
  float* l_part = xzreg + 2097152;
  ush* svB_h = (ush*)t3reg;             // after pinv
  ush* svB_l = (ush*)(t3reg + 262144);
  ush* ttT   = (ush*)regC;              // after pinv
  ush* wqkvT_h = (ush*)wqkvT;
  ush* wqkvT_l = (ush*)(wqkvT + 393216);
  ush* woutT_h = (ush*)woutT;
  ush* woutT_l = (ush*)(woutT + 131072);

  // --- pre-splits ---
  split_flat<<<8192, 256, 0, stream>>>(x, xh, xl, 2097152);
  transpose_split_w<<<dim3(48, 16), 256, 0, stream>>>(Wqkv, wqkvT_h, wqkvT_l, 512, 1536);
  transpose_split_w<<<dim3(16, 16), 256, 0, stream>>>(Wout, woutT_h, woutT_l, 512, 512);

  // --- qkv + landmarks ---
  qkv_mfma<<<dim3(128, 12), 256, 0, stream>>>(xh, xl, wqkvT_h, wqkvT_l,
                                              q_bf, k_bf, v_bf, qlm, klm);

  // --- attn2 + pinv init ---
  sim2_softmax<<<8192, 256, 0, stream>>>(qlm, klm, a2h, a2l);
  colrow_max<<<32, 256, 0, stream>>>(a2h, a2l, red);
  finalize_scale<<<1, 64, 0, stream>>>(red);
  zinit_split<<<dim3(8, 8, 32), 256, 0, stream>>>(a2h, a2l, red,
                                                  zA_[0], zA_[1], zA_[2], zA_[3]);

  // --- pinv Newton-Schulz (split-bf16, pre-split operands) ---
  ush** zc = zA_;
  ush** zn = zB_;
  for (int it = 0; it < 6; ++it) {
    // xz = a2 @ z : out A+B forms
    bgemm_split<<<dim3(2, 4, 32), 256, 0, stream>>>(
        a2h, a2l, zc[2], zc[3], nullptr, nullptr,
        xzA_h, xzA_l, xzB_h, xzB_l, 256, 256, 256, 0.f, -1.f);
    // t2 = 7xz - xz@xz : out B form
    bgemm_split<<<dim3(2, 4, 32), 256, 0, stream>>>(
        xzA_h, xzA_l, xzB_h, xzB_l, xzA_h, xzA_l,
        nullptr, nullptr, t2B_h, t2B_l, 256, 256, 256, 7.f, 1.f);
    // t3 = 15xz - xz@t2 : out B form
    bgemm_split<<<dim3(2, 4, 32), 256, 0, stream>>>(
        xzA_h, xzA_l, t2B_h, t2B_l, xzA_h, xzA_l,
        nullptr, nullptr, t3B_h, t3B_l, 256, 256, 256, 15.f, 1.f);
    // zn = 0.25(13z - z@t3) : out A+B forms
    bgemm_split<<<dim3(2, 4, 32), 256, 0, stream>>>(
        zc[0], zc[1], t3B_h, t3B_l, zc[0], zc[1],
        zn[0], zn[1], zn[2], zn[3], 256, 256, 256, 13.f, 0.25f);
    ush** tp = zc; zc = zn; zn = tp;
  }
  // after 6 swaps zc == zA_ (attn2_inv); zB/xz/t2/t3 regions now free

  // --- sim3 (flash) ---
  vT_cvt_bf<<<dim3(64, 32), 256, 0, stream>>>(v_bf, vT_bf);
  sim3_mfma<<<dim3(4, NCH, 32), 256, 0, stream>>>(qlm, k_bf, vT_bf, O_part, l_part);
  sim3_finalize<<<32, 256, 0, stream>>>(O_part, l_part, svB_h, svB_l);

  // --- tt = attn2_inv @ sv (write ttT = tt^T plain bf16) ---
  bgemm_split<<<dim3(2, 1, 32), 256, 0, stream>>>(
      zc[0], zc[1], svB_h, svB_l, nullptr, nullptr,
      nullptr, nullptr, ttT, nullptr, 256, 64, 256, 0.f, -1.f);

  // --- attn1 + conv + output projection ---
  attn1_mfma<<<dim3(64, 32), 256, 0, stream>>>(q_bf, klm, ttT, outp);
  conv_add_split<<<dim3(64, 32), 256, 0, stream>>>(outp, vT_bf, rker, outph, outpl);
  out_gemm_split<<<dim3(128, 4), 256, 0, stream>>>(outph, outpl, woutT_h, woutT_l, bout, out);
}

// Round 6
// 1023.962 us; speedup vs baseline: 2.1376x; 1.0601x over previous
//
#include <hip/hip_runtime.h>
#include <math.h>

// Problem constants
constexpr int BATCH = 4;
constexpr int SEQ   = 4096;
constexpr int DIMC  = 512;
constexpr int NH    = 8;
constexpr int HD    = 64;
constexpr int NLM   = 256;   // landmarks M
constexpr int LWIN  = 16;    // SEQ / NLM
constexpr int KWIN  = 33;
constexpr int BH    = BATCH * NH; // 32

typedef __attribute__((ext_vector_type(8))) short  bfrag;  // 8 bf16 for MFMA A/B
typedef __attribute__((ext_vector_type(4))) float  ffrag;  // MFMA C/D
typedef __attribute__((ext_vector_type(8))) unsigned short us8;
typedef __attribute__((ext_vector_type(4))) unsigned short us4;
typedef unsigned short ush;

__device__ __forceinline__ ush f2bf(float f) {
  unsigned u = __builtin_bit_cast(unsigned, f);
  return (ush)((u + 0x7FFFu + ((u >> 16) & 1u)) >> 16);
}
__device__ __forceinline__ float bf2f(ush h) {
  unsigned u = ((unsigned)h) << 16;
  return __builtin_bit_cast(float, u);
}
__device__ __forceinline__ void splitf(float f, ush& h, ush& l) {
  h = f2bf(f);
  l = f2bf(f - bf2f(h));
}

// ---------------------------------------------------------------------------
// split_flat: fp32 -> (hi, lo) bf16, elementwise (x pre-split)
// ---------------------------------------------------------------------------
__global__ void split_flat(const float* __restrict__ src, ush* __restrict__ oh,
                           ush* __restrict__ ol, int n4) {
  int i = blockIdx.x * 256 + threadIdx.x;
  if (i >= n4) return;
  float4 f = ((const float4*)src)[i];
  us4 h, l;
  float fs[4] = {f.x, f.y, f.z, f.w};
#pragma unroll
  for (int j = 0; j < 4; ++j) {
    ush hh, ll;
    splitf(fs[j], hh, ll);
    h[j] = hh; l[j] = ll;
  }
  ((us4*)oh)[i] = h;
  ((us4*)ol)[i] = l;
}

// ---------------------------------------------------------------------------
// transpose_split_w: in [R][C] fp32 -> out [C][R] hi/lo bf16 (weights)
// grid (C/32, R/32), 256 threads
// ---------------------------------------------------------------------------
__global__ __launch_bounds__(256) void transpose_split_w(const float* __restrict__ in,
                                                         ush* __restrict__ oh,
                                                         ush* __restrict__ ol,
                                                         int R, int C) {
  __shared__ float T[32][33];
  const int tid = threadIdx.x;
  const int c0 = blockIdx.x * 32, r0 = blockIdx.y * 32;
#pragma unroll
  for (int u = 0; u < 4; ++u) {
    int r = (tid >> 5) * 4 + u, cl = tid & 31;
    T[r][cl] = in[(size_t)(r0 + r) * C + c0 + cl];
  }
  __syncthreads();
#pragma unroll
  for (int u = 0; u < 4; ++u) {
    int cl = (tid >> 5) * 4 + u, rl = tid & 31;
    float f = T[rl][cl];
    ush h, l; splitf(f, h, l);
    size_t o = (size_t)(c0 + cl) * R + r0 + rl;
    oh[o] = h; ol[o] = l;
  }
}

// ---------------------------------------------------------------------------
// K1: qkv split-bf16 MFMA GEMM. Fragment-major LDS (conflict-free: lane->row
// 16B-contiguous, 2-way aliasing = free). BM=BN=128, BK=32, 256 thr.
// Epilogue: q->q_bf (+0.125 scale, + qlm window sums), k->k_bf (+klm),
// v->v_bf. grid (128, 12).
// ---------------------------------------------------------------------------
__global__ __launch_bounds__(256) void qkv_mfma(const ush* __restrict__ xh,
                                                const ush* __restrict__ xl,
                                                const ush* __restrict__ wTh,
                                                const ush* __restrict__ wTl,
                                                ush* __restrict__ q_bf,
                                                ush* __restrict__ k_bf,
                                                ush* __restrict__ v_bf,
                                                float* __restrict__ qlm,
                                                float* __restrict__ klm) {
  __shared__ ush Ast[2][4][128][8];   // [hl][kchunk][row][8] = 16 KB
  __shared__ ush Bst[2][4][128][8];
  const int tid = threadIdx.x;
  const int w = tid >> 6, lane = tid & 63;
  const int lm = lane & 15, lq = lane >> 4;
  const int wm = w >> 1, wn = w & 1;
  const int row0 = blockIdx.x * 128, col0 = blockIdx.y * 128;
  const ffrag fz = {0.f, 0.f, 0.f, 0.f};
  ffrag acc[4][4];
#pragma unroll
  for (int i = 0; i < 4; ++i)
#pragma unroll
    for (int j = 0; j < 4; ++j) acc[i][j] = fz;

  const int srow = tid & 127, shalf = tid >> 7;   // staging: row, k-half
  for (int k0 = 0; k0 < 512; k0 += 32) {
    __syncthreads();
    {
      size_t ao = (size_t)(row0 + srow) * 512 + k0 + shalf * 16;
      *(us8*)&Ast[0][2 * shalf][srow][0]     = *(const us8*)&xh[ao];
      *(us8*)&Ast[0][2 * shalf + 1][srow][0] = *(const us8*)&xh[ao + 8];
      *(us8*)&Ast[1][2 * shalf][srow][0]     = *(const us8*)&xl[ao];
      *(us8*)&Ast[1][2 * shalf + 1][srow][0] = *(const us8*)&xl[ao + 8];
      size_t bo = (size_t)(col0 + srow) * 512 + k0 + shalf * 16;
      *(us8*)&Bst[0][2 * shalf][srow][0]     = *(const us8*)&wTh[bo];
      *(us8*)&Bst[0][2 * shalf + 1][srow][0] = *(const us8*)&wTh[bo + 8];
      *(us8*)&Bst[1][2 * shalf][srow][0]     = *(const us8*)&wTl[bo];
      *(us8*)&Bst[1][2 * shalf + 1][srow][0] = *(const us8*)&wTl[bo + 8];
    }
    __syncthreads();
    bfrag ah[4], al[4], bh[4], bl[4];
#pragma unroll
    for (int mt = 0; mt < 4; ++mt) {
      ah[mt] = *(const bfrag*)&Ast[0][lq][64 * wm + 16 * mt + lm][0];
      al[mt] = *(const bfrag*)&Ast[1][lq][64 * wm + 16 * mt + lm][0];
    }
#pragma unroll
    for (int nt = 0; nt < 4; ++nt) {
      bh[nt] = *(const bfrag*)&Bst[0][lq][64 * wn + 16 * nt + lm][0];
      bl[nt] = *(const bfrag*)&Bst[1][lq][64 * wn + 16 * nt + lm][0];
    }
#pragma unroll
    for (int mt = 0; mt < 4; ++mt)
#pragma unroll
      for (int nt = 0; nt < 4; ++nt) {
        acc[mt][nt] = __builtin_amdgcn_mfma_f32_16x16x32_bf16(ah[mt], bh[nt], acc[mt][nt], 0, 0, 0);
        acc[mt][nt] = __builtin_amdgcn_mfma_f32_16x16x32_bf16(al[mt], bh[nt], acc[mt][nt], 0, 0, 0);
        acc[mt][nt] = __builtin_amdgcn_mfma_f32_16x16x32_bf16(ah[mt], bl[nt], acc[mt][nt], 0, 0, 0);
      }
  }
  // epilogue
#pragma unroll
  for (int mt = 0; mt < 4; ++mt) {
    int rbase = row0 + 64 * wm + 16 * mt;      // 16-aligned -> single window
    int b = rbase >> 12;
    int ntok_base = rbase & 4095;
    int win = ntok_base >> 4;
#pragma unroll
    for (int nt = 0; nt < 4; ++nt) {
      int n_local = 64 * wn + 16 * nt;          // frag col base (h uniform)
      int col = col0 + n_local + lm;
      int which = col >> 9;                     // 0=q 1=k 2=v
      int h = (col >> 6) & 7;
      int d = col & 63;
      int bh_i = b * NH + h;
      float scale = (which == 0) ? 0.125f : 1.0f;
      float vals[4];
      float s = 0.f;
#pragma unroll
      for (int r = 0; r < 4; ++r) {
        vals[r] = acc[mt][nt][r] * scale;
        s += vals[r];
      }
      // write bf16 element copies
      ush* dst = which == 0 ? q_bf : (which == 1 ? k_bf : v_bf);
#pragma unroll
      for (int r = 0; r < 4; ++r) {
        int ntok = ntok_base + 4 * lq + r;
        dst[((size_t)bh_i * SEQ + ntok) * HD + d] = f2bf(vals[r]);
      }
      if (which < 2) {
        // window sum over 16 rows: r-sum + reduce across lq (lane bits 4,5)
        s += __shfl_xor(s, 16);
        s += __shfl_xor(s, 32);
        if (lq == 0) {
          float* lmdst = which == 0 ? qlm : klm;
          lmdst[((size_t)bh_i * NLM + win) * HD + d] = s * (1.0f / LWIN);
        }
      }
    }
  }
}

// ---------------------------------------------------------------------------
// K3: attn2 = softmax(qlm @ klm^T) rows -> split bf16 (a2h/a2l)
// ---------------------------------------------------------------------------
__global__ __launch_bounds__(256) void sim2_softmax(const float* __restrict__ qlm,
                                                    const float* __restrict__ klm,
                                                    ush* __restrict__ a2h,
                                                    ush* __restrict__ a2l) {
  int i = blockIdx.x & 255;
  int bh = blockIdx.x >> 8;
  int j = threadIdx.x;
  __shared__ float qrow[64];
  __shared__ float red[256];
  if (j < 64) qrow[j] = qlm[((size_t)bh * NLM + i) * HD + j];
  __syncthreads();
  const float* kr = klm + ((size_t)bh * NLM + j) * HD;
  float s = 0.f;
#pragma unroll
  for (int d = 0; d < 64; d += 4) {
    float4 kv = *(const float4*)&kr[d];
    s += qrow[d] * kv.x + qrow[d + 1] * kv.y + qrow[d + 2] * kv.z + qrow[d + 3] * kv.w;
  }
  red[j] = s; __syncthreads();
  for (int off = 128; off > 0; off >>= 1) {
    if (j < off) red[j] = fmaxf(red[j], red[j + off]);
    __syncthreads();
  }
  float mx = red[0]; __syncthreads();
  float e = expf(s - mx);
  red[j] = e; __syncthreads();
  for (int off = 128; off > 0; off >>= 1) {
    if (j < off) red[j] += red[j + off];
    __syncthreads();
  }
  float val = e / red[0];
  size_t o = ((size_t)bh * NLM + i) * NLM + j;
  ush h, l; splitf(val, h, l);
  a2h[o] = h; a2l[o] = l;
}

// ---------------------------------------------------------------------------
// K4a: per-bh column/row sums of attn2, block-max of each
// ---------------------------------------------------------------------------
__global__ __launch_bounds__(256) void colrow_max(const ush* __restrict__ a2h,
                                                  const ush* __restrict__ a2l,
                                                  float* __restrict__ red) {
  int bh = blockIdx.x;
  int t = threadIdx.x;
  const size_t base = (size_t)bh * NLM * NLM;
  float cs = 0.f, rs = 0.f;
  for (int i = 0; i < NLM; ++i) {
    size_t o = base + (size_t)i * NLM + t;
    cs += bf2f(a2h[o]) + bf2f(a2l[o]);
  }
  for (int j = 0; j < NLM; ++j) {
    size_t o = base + (size_t)t * NLM + j;
    rs += bf2f(a2h[o]) + bf2f(a2l[o]);
  }
  __shared__ float r1[256], r2[256];
  r1[t] = cs; r2[t] = rs; __syncthreads();
  for (int off = 128; off > 0; off >>= 1) {
    if (t < off) { r1[t] = fmaxf(r1[t], r1[t + off]); r2[t] = fmaxf(r2[t], r2[t + off]); }
    __syncthreads();
  }
  if (t == 0) { red[bh] = r1[0]; red[32 + bh] = r2[0]; }
}

__global__ void finalize_scale(float* __restrict__ red) {
  if (threadIdx.x == 0) {
    float m1 = -1e30f, m2 = -1e30f;
    for (int i = 0; i < BH; ++i) { m1 = fmaxf(m1, red[i]); m2 = fmaxf(m2, red[32 + i]); }
    red[64] = 1.0f / (m1 * m2);
  }
}

// ---------------------------------------------------------------------------
// K4c: z0 = attn2^T * invscale, emitted in A-form ([i][j], transposed) and
// B-form ([j][i] == scaled a2, natural). grid (8, 8, 32), 256 thr, 32x32 tiles
// ---------------------------------------------------------------------------
__global__ __launch_bounds__(256) void zinit_split(const ush* __restrict__ a2h,
                                                   const ush* __restrict__ a2l,
                                                   const float* __restrict__ red,
                                                   ush* __restrict__ zAh, ush* __restrict__ zAl,
                                                   ush* __restrict__ zBh, ush* __restrict__ zBl) {
  __shared__ float T[32][33];
  const int tid = threadIdx.x;
  const int bh = blockIdx.z;
  const int j0 = blockIdx.x * 32, i0 = blockIdx.y * 32;
  const float s = red[64];
  const size_t base = (size_t)bh * NLM * NLM;
#pragma unroll
  for (int u = 0; u < 4; ++u) {
    int jl = (tid >> 5) * 4 + u, il = tid & 31;
    size_t o = base + (size_t)(j0 + jl) * NLM + i0 + il;
    float a = (bf2f(a2h[o]) + bf2f(a2l[o])) * s;
    T[jl][il] = a;
    ush h, l; splitf(a, h, l);
    zBh[o] = h; zBl[o] = l;   // zB[j][i] = a2[j][i]*s
  }
  __syncthreads();
#pragma unroll
  for (int u = 0; u < 4; ++u) {
    int il = (tid >> 5) * 4 + u, jl = tid & 31;
    float a = T[jl][il];
    ush h, l; splitf(a, h, l);
    size_t o = base + (size_t)(i0 + il) * NLM + j0 + jl;  // zA[i][j] = a2[j][i]*s
    zAh[o] = h; zAl[o] = l;
  }
}

// ---------------------------------------------------------------------------
// K5: pinv workhorse, rebuilt for occupancy (round 6):
//   BM=BN=64, BK=32 -> grid (M/64, N/64, 32) = 512 blocks (2/CU at 256x256),
//   fragment-major conflict-free LDS, 2-stage register prefetch of global
//   loads (next k-tile loads in flight under MFMA).
//   C = A@B (split 3-product), Y = coef*(alpha*(Eh+El) - C)
// ---------------------------------------------------------------------------
__global__ __launch_bounds__(256) void bgemm_split(
    const ush* __restrict__ Ah, const ush* __restrict__ Al,
    const ush* __restrict__ Bh, const ush* __restrict__ Bl,
    const ush* __restrict__ Eh, const ush* __restrict__ El,
    ush* oAh, ush* oAl, ush* oBh, ush* oBl,
    int M, int N, int K, float alpha, float coef) {
  __shared__ ush Ast[2][4][64][8];   // [hl][kchunk][row][8] = 4 KB each set
  __shared__ ush Bst[2][4][64][8];
  const int batch = blockIdx.z;
  const size_t abase = (size_t)batch * M * K;
  const size_t bbase = (size_t)batch * N * K;
  const size_t ebase = (size_t)batch * M * N;
  const int tid = threadIdx.x;
  const int w = tid >> 6, lane = tid & 63;
  const int lm = lane & 15, lq = lane >> 4;
  const int wm = w >> 1, wn = w & 1;
  const int row0 = blockIdx.x * 64, col0 = blockIdx.y * 64;
  const ffrag fz = {0.f, 0.f, 0.f, 0.f};
  ffrag acc[2][2] = {{fz, fz}, {fz, fz}};

  // staging assignment: wave w stages k-chunk w for all 64 rows (lane = row)
  const size_t a_off = abase + (size_t)(row0 + lane) * K + w * 8;
  const size_t b_off = bbase + (size_t)(col0 + lane) * K + w * 8;
  us8 ra_h = *(const us8*)&Ah[a_off];
  us8 ra_l = *(const us8*)&Al[a_off];
  us8 rb_h = *(const us8*)&Bh[b_off];
  us8 rb_l = *(const us8*)&Bl[b_off];

  for (int k0 = 0; k0 < K; k0 += 32) {
    __syncthreads();
    *(us8*)&Ast[0][w][lane][0] = ra_h;
    *(us8*)&Ast[1][w][lane][0] = ra_l;
    *(us8*)&Bst[0][w][lane][0] = rb_h;
    *(us8*)&Bst[1][w][lane][0] = rb_l;
    __syncthreads();
    if (k0 + 32 < K) {   // prefetch next k-tile (overlaps MFMA below)
      ra_h = *(const us8*)&Ah[a_off + k0 + 32];
      ra_l = *(const us8*)&Al[a_off + k0 + 32];
      rb_h = *(const us8*)&Bh[b_off + k0 + 32];
      rb_l = *(const us8*)&Bl[b_off + k0 + 32];
    }
    bfrag ah[2], al[2], bhf[2], blf[2];
#pragma unroll
    for (int mt = 0; mt < 2; ++mt) {
      ah[mt] = *(const bfrag*)&Ast[0][lq][32 * wm + 16 * mt + lm][0];
      al[mt] = *(const bfrag*)&Ast[1][lq][32 * wm + 16 * mt + lm][0];
    }
#pragma unroll
    for (int nt = 0; nt < 2; ++nt) {
      bhf[nt] = *(const bfrag*)&Bst[0][lq][32 * wn + 16 * nt + lm][0];
      blf[nt] = *(const bfrag*)&Bst[1][lq][32 * wn + 16 * nt + lm][0];
    }
#pragma unroll
    for (int mt = 0; mt < 2; ++mt)
#pragma unroll
      for (int nt = 0; nt < 2; ++nt) {
        acc[mt][nt] = __builtin_amdgcn_mfma_f32_16x16x32_bf16(ah[mt], bhf[nt], acc[mt][nt], 0, 0, 0);
        acc[mt][nt] = __builtin_amdgcn_mfma_f32_16x16x32_bf16(al[mt], bhf[nt], acc[mt][nt], 0, 0, 0);
        acc[mt][nt] = __builtin_amdgcn_mfma_f32_16x16x32_bf16(ah[mt], blf[nt], acc[mt][nt], 0, 0, 0);
      }
  }
#pragma unroll
  for (int mt = 0; mt < 2; ++mt)
#pragma unroll
    for (int nt = 0; nt < 2; ++nt) {
      int n = col0 + 32 * wn + 16 * nt + lm;
#pragma unroll
      for (int r = 0; r < 4; ++r) {
        int m = row0 + 32 * wm + 16 * mt + 4 * lq + r;
        float c = acc[mt][nt][r];
        float y;
        if (Eh) {
          size_t eo = ebase + (size_t)m * N + n;
          float e = bf2f(Eh[eo]) + bf2f(El[eo]);
          y = coef * (alpha * e - c);
        } else {
          y = -coef * c;
        }
        ush h, l; splitf(y, h, l);
        if (oAh) {
          size_t o = ebase + (size_t)m * N + n;
          oAh[o] = h; oAl[o] = l;
        }
        if (oBh) {
          size_t o = (size_t)batch * N * M + (size_t)n * M + m;
          oBh[o] = h;
          if (oBl) oBl[o] = l;
        }
      }
    }
}

// ---------------------------------------------------------------------------
// vT_cvt_bf: v_bf [bh][n][d] -> vT_bf [bh][d][n]. grid (64, 32)
// ---------------------------------------------------------------------------
__global__ __launch_bounds__(256) void vT_cvt_bf(const ush* __restrict__ v_bf,
                                                 ush* __restrict__ vT) {
  __shared__ ush T[64][72];
  const int bh = blockIdx.y;
  const int n0 = blockIdx.x * 64;
  const int tid = threadIdx.x;
  {
    int n = tid >> 2, off = (tid & 3) * 16;
    const ush* src = &v_bf[((size_t)bh * SEQ + n0 + n) * HD + off];
    *(us8*)&T[n][off] = *(const us8*)src;
    *(us8*)&T[n][off + 8] = *(const us8*)&src[8];
  }
  __syncthreads();
  {
    int d = tid >> 2, noff = (tid & 3) * 16;
    us8 o0, o1;
#pragma unroll
    for (int j = 0; j < 8; ++j) o0[j] = T[noff + j][d];
#pragma unroll
    for (int j = 0; j < 8; ++j) o1[j] = T[noff + 8 + j][d];
    ush* dst = &vT[((size_t)bh * HD + d) * SEQ + n0 + noff];
    *(us8*)dst = o0;
    *(us8*)&dst[8] = o1;
  }
}

// ---------------------------------------------------------------------------
// K6: sim3 flash via MFMA, no max-subtraction (scores tiny). n-split NCH ways.
// ---------------------------------------------------------------------------
constexpr int NCH = 4;
__global__ __launch_bounds__(256) void sim3_mfma(const float* __restrict__ qlm,
                                                 const ush* __restrict__ k_bf,
                                                 const ush* __restrict__ vT_bf,
                                                 float* __restrict__ O_part,
                                                 float* __restrict__ l_part) {
  constexpr int CHUNK = SEQ / NCH;  // 1024
  __shared__ ush Qs[64][72];
  __shared__ ush Ks[128][72];
  __shared__ ush Vs[64][136];
  __shared__ ush Ps[64][136];
  const int bh = blockIdx.z;
  const int m0 = blockIdx.x * 64;
  const int n_base = blockIdx.y * CHUNK;
  const int tid = threadIdx.x;
  const int w = tid >> 6, lane = tid & 63;
  const int lm = lane & 15, lq = lane >> 4;
  {
    int m = tid >> 2, off = (tid & 3) * 16;
    const float* src = &qlm[((size_t)bh * NLM + m0 + m) * HD + off];
    us8 o0, o1;
#pragma unroll
    for (int j = 0; j < 8; ++j) o0[j] = f2bf(src[j]);
#pragma unroll
    for (int j = 0; j < 8; ++j) o1[j] = f2bf(src[8 + j]);
    *(us8*)&Qs[m][off] = o0;
    *(us8*)&Qs[m][off + 8] = o1;
  }
  const ffrag fz = {0.f, 0.f, 0.f, 0.f};
  ffrag O[4] = {fz, fz, fz, fz};
  float lsum[4] = {0.f, 0.f, 0.f, 0.f};

  for (int n0 = 0; n0 < CHUNK; n0 += 128) {
    __syncthreads();
    {
      int n = tid >> 1, off = (tid & 1) * 32;
      const ush* src = &k_bf[((size_t)bh * SEQ + n_base + n0 + n) * HD + off];
#pragma unroll
      for (int u = 0; u < 4; ++u) *(us8*)&Ks[n][off + 8 * u] = *(const us8*)&src[8 * u];
    }
    {
      int d = tid >> 2, off = (tid & 3) * 32;
      const ush* src = &vT_bf[((size_t)bh * HD + d) * SEQ + n_base + n0 + off];
#pragma unroll
      for (int u = 0; u < 4; ++u) *(us8*)&Vs[d][off + 8 * u] = *(const us8*)&src[8 * u];
    }
    __syncthreads();
    ffrag S[8] = {fz, fz, fz, fz, fz, fz, fz, fz};
#pragma unroll
    for (int ks = 0; ks < 2; ++ks) {
      bfrag a = *(const bfrag*)&Qs[16 * w + lm][32 * ks + 8 * lq];
#pragma unroll
      for (int t = 0; t < 8; ++t) {
        bfrag b = *(const bfrag*)&Ks[16 * t + lm][32 * ks + 8 * lq];
        S[t] = __builtin_amdgcn_mfma_f32_16x16x32_bf16(a, b, S[t], 0, 0, 0);
      }
    }
#pragma unroll
    for (int t = 0; t < 8; ++t)
#pragma unroll
      for (int r = 0; r < 4; ++r) {
        float p = __expf(S[t][r]);
        lsum[r] += p;
        Ps[16 * w + 4 * lq + r][16 * t + lm] = f2bf(p);
      }
    __syncthreads();
#pragma unroll
    for (int kk = 0; kk < 4; ++kk) {
      bfrag a = *(const bfrag*)&Ps[16 * w + lm][32 * kk + 8 * lq];
#pragma unroll
      for (int t2 = 0; t2 < 4; ++t2) {
        bfrag b = *(const bfrag*)&Vs[16 * t2 + lm][32 * kk + 8 * lq];
        O[t2] = __builtin_amdgcn_mfma_f32_16x16x32_bf16(a, b, O[t2], 0, 0, 0);
      }
    }
  }
#pragma unroll
  for (int r = 0; r < 4; ++r) {
#pragma unroll
    for (int off = 1; off < 16; off <<= 1) lsum[r] += __shfl_xor(lsum[r], off);
  }
  const size_t pbase = (size_t)blockIdx.y * 32 + bh;
  if (lm == 0) {
#pragma unroll
    for (int r = 0; r < 4; ++r)
      l_part[pbase * NLM + m0 + 16 * w + 4 * lq + r] = lsum[r];
  }
#pragma unroll
  for (int t2 = 0; t2 < 4; ++t2)
#pragma unroll
    for (int r = 0; r < 4; ++r) {
      int m = m0 + 16 * w + 4 * lq + r;
      int d = 16 * t2 + lm;
      O_part[(pbase * NLM + m) * HD + d] = O[t2][r];
    }
}

// sim3_finalize: combine partials, write sv in B-form split ([d][m]).
// grid (32), 256 threads, one block per bh.
__global__ __launch_bounds__(256) void sim3_finalize(const float* __restrict__ O_part,
                                                     const float* __restrict__ l_part,
                                                     ush* __restrict__ svBh,
                                                     ush* __restrict__ svBl) {
  __shared__ float acc[256 * 65];
  __shared__ float ls[256];
  const int bh = blockIdx.x;
  const int tid = threadIdx.x;
  for (int e = tid; e < 16384; e += 256) {
    float s = 0.f;
#pragma unroll
    for (int c = 0; c < NCH; ++c) s += O_part[(((size_t)(c * 32 + bh)) << 14) + e];
    acc[(e >> 6) * 65 + (e & 63)] = s;
  }
  {
    float s = 0.f;
#pragma unroll
    for (int c = 0; c < NCH; ++c) s += l_part[(size_t)(c * 32 + bh) * NLM + tid];
    ls[tid] = s;
  }
  __syncthreads();
  for (int e = tid; e < 16384; e += 256) {
    int d = e >> 8, m = e & 255;
    float val = acc[m * 65 + d] / ls[m];
    ush h, l; splitf(val, h, l);
    size_t o = ((size_t)bh * HD + d) * NLM + m;
    svBh[o] = h; svBl[o] = l;
  }
}

// ---------------------------------------------------------------------------
// K8: attn1 via MFMA: outp = softmax(q_bf @ klm^T) @ tt  (fp32 softmax)
// grid (64, 32), 256 thr. Block: 64 q-rows, full 256 landmarks.
// ---------------------------------------------------------------------------
__global__ __launch_bounds__(256) void attn1_mfma(const ush* __restrict__ q_bf,
                                                  const float* __restrict__ klm,
                                                  const ush* __restrict__ ttT,
                                                  float* __restrict__ outp) {
  __shared__ ush bufA[256 * 72];   // klm bf16 [256][72] then ttT [64][264]
  __shared__ ush bufB[64 * 264];   // qs [64][72] then Ps [64][264]
  const int bh = blockIdx.y;
  const int b = bh >> 3, h = bh & 7;
  const int i0 = blockIdx.x * 64;
  const int tid = threadIdx.x;
  const int w = tid >> 6, lane = tid & 63;
  const int lm = lane & 15, lq = lane >> 4;
  // stage qs (q_bf rows i0..i0+63) into bufB as [64][72]
  {
    int m = tid >> 2, off = (tid & 3) * 16;
    const ush* src = &q_bf[((size_t)bh * SEQ + i0 + m) * HD + off];
    *(us8*)&bufB[m * 72 + off] = *(const us8*)src;
    *(us8*)&bufB[m * 72 + off + 8] = *(const us8*)&src[8];
  }
  // stage klm (fp32 -> bf16) into bufA as [256][72]
  {
    const float* kb = klm + (size_t)bh * NLM * HD;
#pragma unroll
    for (int u = 0; u < 16; ++u) {
      int e4 = u * 256 + tid;           // float4 index, 4096 total
      float4 f = ((const float4*)kb)[e4];
      int row = e4 >> 4, col = (e4 & 15) * 4;
      ush* p = &bufA[row * 72 + col];
      p[0] = f2bf(f.x); p[1] = f2bf(f.y); p[2] = f2bf(f.z); p[3] = f2bf(f.w);
    }
  }
  __syncthreads();
  // phase 1: S = q @ klm^T  (wave w owns rows 16w..16w+15)
  const ffrag fz = {0.f, 0.f, 0.f, 0.f};
  ffrag S[16];
#pragma unroll
  for (int t = 0; t < 16; ++t) S[t] = fz;
#pragma unroll
  for (int ks = 0; ks < 2; ++ks) {
    bfrag a = *(const bfrag*)&bufB[(16 * w + lm) * 72 + 32 * ks + 8 * lq];
#pragma unroll
    for (int t = 0; t < 16; ++t) {
      bfrag bb = *(const bfrag*)&bufA[(16 * t + lm) * 72 + 32 * ks + 8 * lq];
      S[t] = __builtin_amdgcn_mfma_f32_16x16x32_bf16(a, bb, S[t], 0, 0, 0);
    }
  }
  // softmax over 256 cols per row (rows 4lq+r within wave strip)
  float rinv[4];
  float ev[16][4];
#pragma unroll
  for (int r = 0; r < 4; ++r) {
    float mx = -INFINITY;
#pragma unroll
    for (int t = 0; t < 16; ++t) mx = fmaxf(mx, S[t][r]);
#pragma unroll
    for (int off = 1; off < 16; off <<= 1) mx = fmaxf(mx, __shfl_xor(mx, off));
    float sm = 0.f;
#pragma unroll
    for (int t = 0; t < 16; ++t) { ev[t][r] = __expf(S[t][r] - mx); sm += ev[t][r]; }
#pragma unroll
    for (int off = 1; off < 16; off <<= 1) sm += __shfl_xor(sm, off);
    rinv[r] = 1.0f / sm;
  }
  __syncthreads();   // qs + klm reads done everywhere
  // write P (bf16) into bufB as [64][264]; stage ttT into bufA as [64][264]
#pragma unroll
  for (int t = 0; t < 16; ++t)
#pragma unroll
    for (int r = 0; r < 4; ++r)
      bufB[(16 * w + 4 * lq + r) * 264 + 16 * t + lm] = f2bf(ev[t][r]);
  {
    const ush* tb = ttT + (size_t)bh * HD * NLM;
#pragma unroll
    for (int u = 0; u < 8; ++u) {
      int e8 = u * 256 + tid;           // us8 index, 2048 total
      int row = e8 >> 5, col = (e8 & 31) * 8;
      *(us8*)&bufA[row * 264 + col] = *(const us8*)&tb[row * NLM + col];
    }
  }
  __syncthreads();
  // phase 2: O = P @ tt   (A = Ps rows 16w.., B = ttT rows = d)
  ffrag O[4] = {fz, fz, fz, fz};
#pragma unroll
  for (int kk = 0; kk < 8; ++kk) {
    bfrag a = *(const bfrag*)&bufB[(16 * w + lm) * 264 + 32 * kk + 8 * lq];
#pragma unroll
    for (int t2 = 0; t2 < 4; ++t2) {
      bfrag bb = *(const bfrag*)&bufA[(16 * t2 + lm) * 264 + 32 * kk + 8 * lq];
      O[t2] = __builtin_amdgcn_mfma_f32_16x16x32_bf16(a, bb, O[t2], 0, 0, 0);
    }
  }
#pragma unroll
  for (int t2 = 0; t2 < 4; ++t2)
#pragma unroll
    for (int r = 0; r < 4; ++r) {
      int i = i0 + 16 * w + 4 * lq + r;
      int d = 16 * t2 + lm;
      outp[((size_t)b * SEQ + i) * DIMC + h * HD + d] = O[t2][r] * rinv[r];
    }
}

// ---------------------------------------------------------------------------
// K9: conv add + split: outp(fp32) + depthwise conv(vT_bf) -> outph/outpl
// grid (64, 32): block = 64 seq positions x 64 dims for one bh
// ---------------------------------------------------------------------------
__global__ __launch_bounds__(256) void conv_add_split(const float* __restrict__ outp,
                                                      const ush* __restrict__ vT,
                                                      const float* __restrict__ kern,
                                                      ush* __restrict__ oh,
                                                      ush* __restrict__ ol) {
  __shared__ float vt[64 * 97];   // [d][96+1], cols n0-16 .. n0+79
  __shared__ float ks[KWIN];
  const int bh = blockIdx.y;
  const int b = bh >> 3, hh = bh & 7;
  const int n0 = blockIdx.x * 64;
  const int tid = threadIdx.x;
  if (tid < KWIN) ks[tid] = kern[hh * KWIN + tid];
  for (int e = tid; e < 64 * 96; e += 256) {
    int d = e / 96, c = e % 96;
    int n = n0 - 16 + c;
    vt[d * 97 + c] = (n >= 0 && n < SEQ) ? bf2f(vT[((size_t)bh * HD + d) * SEQ + n]) : 0.f;
  }
  __syncthreads();
  const int d = tid & 63, g = tid >> 6;
  float wreg[48];
#pragma unroll
  for (int j = 0; j < 48; ++j) wreg[j] = vt[d * 97 + g * 16 + j];
#pragma unroll
  for (int nn = 0; nn < 16; ++nn) {
    float s = 0.f;
#pragma unroll
    for (int t = 0; t < KWIN; ++t) s = fmaf(ks[t], wreg[nn + t], s);
    int n = n0 + g * 16 + nn;
    size_t o = ((size_t)b * SEQ + n) * DIMC + hh * HD + d;
    float val = outp[o] + s;
    ush h, l; splitf(val, h, l);
    oh[o] = h; ol[o] = l;
  }
}

// ---------------------------------------------------------------------------
// K10: out = outp_split @ WoutT_split + bias. Fragment-major LDS.
// BM=BN=128, grid (128, 4)
// ---------------------------------------------------------------------------
__global__ __launch_bounds__(256) void out_gemm_split(const ush* __restrict__ ah_g,
                                                      const ush* __restrict__ al_g,
                                                      const ush* __restrict__ bh_g,
                                                      const ush* __restrict__ bl_g,
                                                      const float* __restrict__ bias,
                                                      float* __restrict__ out) {
  __shared__ ush Ast[2][4][128][8];
  __shared__ ush Bst[2][4][128][8];
  const int tid = threadIdx.x;
  const int w = tid >> 6, lane = tid & 63;
  const int lm = lane & 15, lq = lane >> 4;
  const int wm = w >> 1, wn = w & 1;
  const int row0 = blockIdx.x * 128, col0 = blockIdx.y * 128;
  const ffrag fz = {0.f, 0.f, 0.f, 0.f};
  ffrag acc[4][4];
#pragma unroll
  for (int i = 0; i < 4; ++i)
#pragma unroll
    for (int j = 0; j < 4; ++j) acc[i][j] = fz;

  const int srow = tid & 127, shalf = tid >> 7;
  for (int k0 = 0; k0 < 512; k0 += 32) {
    __syncthreads();
    {
      size_t ao = (size_t)(row0 + srow) * 512 + k0 + shalf * 16;
      *(us8*)&Ast[0][2 * shalf][srow][0]     = *(const us8*)&ah_g[ao];
      *(us8*)&Ast[0][2 * shalf + 1][srow][0] = *(const us8*)&ah_g[ao + 8];
      *(us8*)&Ast[1][2 * shalf][srow][0]     = *(const us8*)&al_g[ao];
      *(us8*)&Ast[1][2 * shalf + 1][srow][0] = *(const us8*)&al_g[ao + 8];
      size_t bo = (size_t)(col0 + srow) * 512 + k0 + shalf * 16;
      *(us8*)&Bst[0][2 * shalf][srow][0]     = *(const us8*)&bh_g[bo];
      *(us8*)&Bst[0][2 * shalf + 1][srow][0] = *(const us8*)&bh_g[bo + 8];
      *(us8*)&Bst[1][2 * shalf][srow][0]     = *(const us8*)&bl_g[bo];
      *(us8*)&Bst[1][2 * shalf + 1][srow][0] = *(const us8*)&bl_g[bo + 8];
    }
    __syncthreads();
    bfrag ah[4], al[4], bh[4], bl[4];
#pragma unroll
    for (int mt = 0; mt < 4; ++mt) {
      ah[mt] = *(const bfrag*)&Ast[0][lq][64 * wm + 16 * mt + lm][0];
      al[mt] = *(const bfrag*)&Ast[1][lq][64 * wm + 16 * mt + lm][0];
    }
#pragma unroll
    for (int nt = 0; nt < 4; ++nt) {
      bh[nt] = *(const bfrag*)&Bst[0][lq][64 * wn + 16 * nt + lm][0];
      bl[nt] = *(const bfrag*)&Bst[1][lq][64 * wn + 16 * nt + lm][0];
    }
#pragma unroll
    for (int mt = 0; mt < 4; ++mt)
#pragma unroll
      for (int nt = 0; nt < 4; ++nt) {
        acc[mt][nt] = __builtin_amdgcn_mfma_f32_16x16x32_bf16(ah[mt], bh[nt], acc[mt][nt], 0, 0, 0);
        acc[mt][nt] = __builtin_amdgcn_mfma_f32_16x16x32_bf16(al[mt], bh[nt], acc[mt][nt], 0, 0, 0);
        acc[mt][nt] = __builtin_amdgcn_mfma_f32_16x16x32_bf16(ah[mt], bl[nt], acc[mt][nt], 0, 0, 0);
      }
  }
#pragma unroll
  for (int mt = 0; mt < 4; ++mt)
#pragma unroll
    for (int nt = 0; nt < 4; ++nt) {
      int n = col0 + 64 * wn + 16 * nt + lm;
      float bv = bias[n];
#pragma unroll
      for (int r = 0; r < 4; ++r) {
        int m = row0 + 64 * wm + 16 * mt + 4 * lq + r;
        out[(size_t)m * 512 + n] = acc[mt][nt][r] + bv;
      }
    }
}

// ---------------------------------------------------------------------------
extern "C" void kernel_launch(void* const* d_in, const int* in_sizes, int n_in,
                              void* d_out, int out_size, void* d_ws, size_t ws_size,
                              hipStream_t stream) {
  const float* x    = (const float*)d_in[0];
  const float* Wqkv = (const float*)d_in[1];
  const float* Wout = (const float*)d_in[2];
  const float* bout = (const float*)d_in[3];
  const float* rker = (const float*)d_in[4];
  float* out = (float*)d_out;
  float* ws = (float*)d_ws;

  // workspace layout (float-element offsets), total ~186.6 MB
  ush*   v_bf   = (ush*)(ws);                          // 8388608 ush (4194304 f)
  ush*   q_bf   = (ush*)(ws + 4194304);                // 8388608 ush
  float* regA   = ws + 8388608;                        // 8388608 f: k_bf -> outp
  float* regB   = ws + 16777216;                       // 8388608 f: xh+xl -> outph+outpl
  float* qlm    = ws + 25165824;                       // 524288
  float* klm    = ws + 25690112;                       // 524288
  float* regC   = ws + 26214400;                       // 2097152 f: t2B(h,l) / ttT
  float* a2reg  = ws + 28311552;                       // 2097152 f: a2h+a2l
  float* zAreg  = ws + 30408704;                       // 4194304 f
  float* zBreg  = ws + 34603008;                       // 4194304 f (later vT_bf)
  float* xzreg  = ws + 38797312;                       // 4194304 f (later O_part/l_part)
  float* t3reg  = ws + 43515904;                       // 2097152 f (later svB)
  float* wqkvT  = ws + 45613056;                       // 786432 f
  float* woutT  = ws + 46399488;                       // 262144 f
  float* red    = ws + 46661632;                       // 128

  ush* k_bf  = (ush*)regA;
  float* outp = regA;
  // xh occupies 4194304 floats of regB; xl starts AFTER it (r4 fix)
  ush* xh = (ush*)regB;                 // 8388608 ush = [regB, regB+4194304f)
  ush* xl = (ush*)(regB + 4194304);     // 8388608 ush = [regB+4194304f, +8388608f)
  ush* outph = (ush*)regB;
  ush* outpl = (ush*)(regB + 4194304);
  ush* a2h = (ush*)a2reg;               // 2097152 ush each
  ush* a2l = (ush*)(a2reg + 1048576);
  // z buffers: 4 arrays of 2097152 ush each (Ah, Al, Bh, Bl)
  ush* zA_[4] = {(ush*)zAreg, (ush*)(zAreg + 1048576), (ush*)(zAreg + 2097152), (ush*)(zAreg + 3145728)};
  ush* zB_[4] = {(ush*)zBreg, (ush*)(zBreg + 1048576), (ush*)(zBreg + 2097152), (ush*)(zBreg + 3145728)};
  ush* xzA_h = (ush*)xzreg;             // xz A-form + B-form
  ush* xzA_l = (ush*)(xzreg + 1048576);
  ush* xzB_h = (ush*)(xzreg + 2097152);
  ush* xzB_l = (ush*)(xzreg + 3145728);
  ush* t2B_h = (ush*)regC;
  ush* t2B_l = (ush*)(regC + 1048576);
  ush* t3B_h = (ush*)t3reg;
  ush* t3B_l = (ush*)(t3reg + 1048576);
  ush* vT_bf = (ush*)zBreg;             // after pinv
  float* O_part = xzreg;                // after pinv
  float* l_part = xzreg + 2097152;
  ush* svB_h = (ush*)t3reg;             // after pinv
  ush* svB_l = (ush*)(t3reg + 262144);
  ush* ttT   = (ush*)regC;              // after pinv
  ush* wqkvT_h = (ush*)wqkvT;
  ush* wqkvT_l = (ush*)(wqkvT + 393216);
  ush* woutT_h = (ush*)woutT;
  ush* woutT_l = (ush*)(woutT + 131072);

  // --- pre-splits ---
  split_flat<<<8192, 256, 0, stream>>>(x, xh, xl, 2097152);
  transpose_split_w<<<dim3(48, 16), 256, 0, stream>>>(Wqkv, wqkvT_h, wqkvT_l, 512, 1536);
  transpose_split_w<<<dim3(16, 16), 256, 0, stream>>>(Wout, woutT_h, woutT_l, 512, 512);

  // --- qkv + landmarks ---
  qkv_mfma<<<dim3(128, 12), 256, 0, stream>>>(xh, xl, wqkvT_h, wqkvT_l,
                                              q_bf, k_bf, v_bf, qlm, klm);

  // --- attn2 + pinv init ---
  sim2_softmax<<<8192, 256, 0, stream>>>(qlm, klm, a2h, a2l);
  colrow_max<<<32, 256, 0, stream>>>(a2h, a2l, red);
  finalize_scale<<<1, 64, 0, stream>>>(red);
  zinit_split<<<dim3(8, 8, 32), 256, 0, stream>>>(a2h, a2l, red,
                                                  zA_[0], zA_[1], zA_[2], zA_[3]);

  // --- pinv Newton-Schulz (split-bf16, pre-split operands) ---
  ush** zc = zA_;
  ush** zn = zB_;
  for (int it = 0; it < 6; ++it) {
    // xz = a2 @ z : out A+B forms
    bgemm_split<<<dim3(4, 4, 32), 256, 0, stream>>>(
        a2h, a2l, zc[2], zc[3], nullptr, nullptr,
        xzA_h, xzA_l, xzB_h, xzB_l, 256, 256, 256, 0.f, -1.f);
    // t2 = 7xz - xz@xz : out B form
    bgemm_split<<<dim3(4, 4, 32), 256, 0, stream>>>(
        xzA_h, xzA_l, xzB_h, xzB_l, xzA_h, xzA_l,
        nullptr, nullptr, t2B_h, t2B_l, 256, 256, 256, 7.f, 1.f);
    // t3 = 15xz - xz@t2 : out B form
    bgemm_split<<<dim3(4, 4, 32), 256, 0, stream>>>(
        xzA_h, xzA_l, t2B_h, t2B_l, xzA_h, xzA_l,
        nullptr, nullptr, t3B_h, t3B_l, 256, 256, 256, 15.f, 1.f);
    // zn = 0.25(13z - z@t3) : out A+B forms
    bgemm_split<<<dim3(4, 4, 32), 256, 0, stream>>>(
        zc[0], zc[1], t3B_h, t3B_l, zc[0], zc[1],
        zn[0], zn[1], zn[2], zn[3], 256, 256, 256, 13.f, 0.25f);
    ush** tp = zc; zc = zn; zn = tp;
  }
  // after 6 swaps zc == zA_ (attn2_inv); zB/xz/t2/t3 regions now free

  // --- sim3 (flash) ---
  vT_cvt_bf<<<dim3(64, 32), 256, 0, stream>>>(v_bf, vT_bf);
  sim3_mfma<<<dim3(4, NCH, 32), 256, 0, stream>>>(qlm, k_bf, vT_bf, O_part, l_part);
  sim3_finalize<<<32, 256, 0, stream>>>(O_part, l_part, svB_h, svB_l);

  // --- tt = attn2_inv @ sv (write ttT = tt^T plain bf16) ---
  bgemm_split<<<dim3(4, 1, 32), 256, 0, stream>>>(
      zc[0], zc[1], svB_h, svB_l, nullptr, nullptr,
      nullptr, nullptr, ttT, nullptr, 256, 64, 256, 0.f, -1.f);

  // --- attn1 + conv + output projection ---
  attn1_mfma<<<dim3(64, 32), 256, 0, stream>>>(q_bf, klm, ttT, outp);
  conv_add_split<<<dim3(64, 32), 256, 0, stream>>>(outp, vT_bf, rker, outph, outpl);
  out_gemm_split<<<dim3(128, 4), 256, 0, stream>>>(outph, outpl, woutT_h, woutT_l, bout, out);
}

// Round 7
// 938.465 us; speedup vs baseline: 2.3324x; 1.0911x over previous
//
#include <hip/hip_runtime.h>
#include <math.h>

// Problem constants
constexpr int BATCH = 4;
constexpr int SEQ   = 4096;
constexpr int DIMC  = 512;
constexpr int NH    = 8;
constexpr int HD    = 64;
constexpr int NLM   = 256;   // landmarks M
constexpr int LWIN  = 16;    // SEQ / NLM
constexpr int KWIN  = 33;
constexpr int BH    = BATCH * NH; // 32

typedef __attribute__((ext_vector_type(8))) short  bfrag;  // 8 bf16 for MFMA A/B
typedef __attribute__((ext_vector_type(4))) float  ffrag;  // MFMA C/D
typedef __attribute__((ext_vector_type(8))) unsigned short us8;
typedef __attribute__((ext_vector_type(4))) unsigned short us4;
typedef unsigned short ush;

__device__ __forceinline__ ush f2bf(float f) {
  unsigned u = __builtin_bit_cast(unsigned, f);
  return (ush)((u + 0x7FFFu + ((u >> 16) & 1u)) >> 16);
}
__device__ __forceinline__ float bf2f(ush h) {
  unsigned u = ((unsigned)h) << 16;
  return __builtin_bit_cast(float, u);
}
__device__ __forceinline__ void splitf(float f, ush& h, ush& l) {
  h = f2bf(f);
  l = f2bf(f - bf2f(h));
}
// async global->LDS, 16B per lane: LDS dest = base + lane*16 (wave-uniform base)
__device__ __forceinline__ void gl_lds16(const ush* g, ush* l) {
  __builtin_amdgcn_global_load_lds(
      (const __attribute__((address_space(1))) void*)g,
      (__attribute__((address_space(3))) void*)l, 16, 0, 0);
}

// ---------------------------------------------------------------------------
// split_flat: fp32 -> (hi, lo) bf16, elementwise (x pre-split)
// ---------------------------------------------------------------------------
__global__ void split_flat(const float* __restrict__ src, ush* __restrict__ oh,
                           ush* __restrict__ ol, int n4) {
  int i = blockIdx.x * 256 + threadIdx.x;
  if (i >= n4) return;
  float4 f = ((const float4*)src)[i];
  us4 h, l;
  float fs[4] = {f.x, f.y, f.z, f.w};
#pragma unroll
  for (int j = 0; j < 4; ++j) {
    ush hh, ll;
    splitf(fs[j], hh, ll);
    h[j] = hh; l[j] = ll;
  }
  ((us4*)oh)[i] = h;
  ((us4*)ol)[i] = l;
}

// ---------------------------------------------------------------------------
// transpose_split_w: in [R][C] fp32 -> out [C][R] hi/lo bf16 (weights)
// ---------------------------------------------------------------------------
__global__ __launch_bounds__(256) void transpose_split_w(const float* __restrict__ in,
                                                         ush* __restrict__ oh,
                                                         ush* __restrict__ ol,
                                                         int R, int C) {
  __shared__ float T[32][33];
  const int tid = threadIdx.x;
  const int c0 = blockIdx.x * 32, r0 = blockIdx.y * 32;
#pragma unroll
  for (int u = 0; u < 4; ++u) {
    int r = (tid >> 5) * 4 + u, cl = tid & 31;
    T[r][cl] = in[(size_t)(r0 + r) * C + c0 + cl];
  }
  __syncthreads();
#pragma unroll
  for (int u = 0; u < 4; ++u) {
    int cl = (tid >> 5) * 4 + u, rl = tid & 31;
    float f = T[rl][cl];
    ush h, l; splitf(f, h, l);
    size_t o = (size_t)(c0 + cl) * R + r0 + rl;
    oh[o] = h; ol[o] = l;
  }
}

// ---------------------------------------------------------------------------
// K1: qkv split-bf16 MFMA GEMM — ROUND-5 LAYOUT (measured 97us / 798 TF eff;
// r6 fragment-major plane layout regressed to 133us — reverted).
// BM=BN=128, BK=32, 256 thr. Epilogue: q/k/v bf16 + fused landmark pooling.
// ---------------------------------------------------------------------------
__global__ __launch_bounds__(256) void qkv_mfma(const ush* __restrict__ xh,
                                                const ush* __restrict__ xl,
                                                const ush* __restrict__ wTh,
                                                const ush* __restrict__ wTl,
                                                ush* __restrict__ q_bf,
                                                ush* __restrict__ k_bf,
                                                ush* __restrict__ v_bf,
                                                float* __restrict__ qlm,
                                                float* __restrict__ klm) {
  __shared__ ush Ash[128][40], Asl[128][40];
  __shared__ ush Bsh[128][40], Bsl[128][40];
  const int tid = threadIdx.x;
  const int w = tid >> 6, lane = tid & 63;
  const int lm = lane & 15, lq = lane >> 4;
  const int wm = w >> 1, wn = w & 1;
  const int row0 = blockIdx.x * 128, col0 = blockIdx.y * 128;
  const ffrag fz = {0.f, 0.f, 0.f, 0.f};
  ffrag acc[4][4];
#pragma unroll
  for (int i = 0; i < 4; ++i)
#pragma unroll
    for (int j = 0; j < 4; ++j) acc[i][j] = fz;

  const int sm = tid >> 1, skoff = (tid & 1) * 16;
  for (int k0 = 0; k0 < 512; k0 += 32) {
    __syncthreads();
    {
      size_t ao = (size_t)(row0 + sm) * 512 + k0 + skoff;
      *(us8*)&Ash[sm][skoff]     = *(const us8*)&xh[ao];
      *(us8*)&Ash[sm][skoff + 8] = *(const us8*)&xh[ao + 8];
      *(us8*)&Asl[sm][skoff]     = *(const us8*)&xl[ao];
      *(us8*)&Asl[sm][skoff + 8] = *(const us8*)&xl[ao + 8];
      size_t bo = (size_t)(col0 + sm) * 512 + k0 + skoff;
      *(us8*)&Bsh[sm][skoff]     = *(const us8*)&wTh[bo];
      *(us8*)&Bsh[sm][skoff + 8] = *(const us8*)&wTh[bo + 8];
      *(us8*)&Bsl[sm][skoff]     = *(const us8*)&wTl[bo];
      *(us8*)&Bsl[sm][skoff + 8] = *(const us8*)&wTl[bo + 8];
    }
    __syncthreads();
    bfrag ah[4], al[4], bh[4], bl[4];
#pragma unroll
    for (int mt = 0; mt < 4; ++mt) {
      ah[mt] = *(const bfrag*)&Ash[64 * wm + 16 * mt + lm][8 * lq];
      al[mt] = *(const bfrag*)&Asl[64 * wm + 16 * mt + lm][8 * lq];
    }
#pragma unroll
    for (int nt = 0; nt < 4; ++nt) {
      bh[nt] = *(const bfrag*)&Bsh[64 * wn + 16 * nt + lm][8 * lq];
      bl[nt] = *(const bfrag*)&Bsl[64 * wn + 16 * nt + lm][8 * lq];
    }
#pragma unroll
    for (int mt = 0; mt < 4; ++mt)
#pragma unroll
      for (int nt = 0; nt < 4; ++nt) {
        acc[mt][nt] = __builtin_amdgcn_mfma_f32_16x16x32_bf16(ah[mt], bh[nt], acc[mt][nt], 0, 0, 0);
        acc[mt][nt] = __builtin_amdgcn_mfma_f32_16x16x32_bf16(al[mt], bh[nt], acc[mt][nt], 0, 0, 0);
        acc[mt][nt] = __builtin_amdgcn_mfma_f32_16x16x32_bf16(ah[mt], bl[nt], acc[mt][nt], 0, 0, 0);
      }
  }
  // epilogue
#pragma unroll
  for (int mt = 0; mt < 4; ++mt) {
    int rbase = row0 + 64 * wm + 16 * mt;      // 16-aligned -> single window
    int b = rbase >> 12;
    int ntok_base = rbase & 4095;
    int win = ntok_base >> 4;
#pragma unroll
    for (int nt = 0; nt < 4; ++nt) {
      int n_local = 64 * wn + 16 * nt;          // frag col base (h uniform)
      int col = col0 + n_local + lm;
      int which = col >> 9;                     // 0=q 1=k 2=v
      int h = (col >> 6) & 7;
      int d = col & 63;
      int bh_i = b * NH + h;
      float scale = (which == 0) ? 0.125f : 1.0f;
      float vals[4];
      float s = 0.f;
#pragma unroll
      for (int r = 0; r < 4; ++r) {
        vals[r] = acc[mt][nt][r] * scale;
        s += vals[r];
      }
      ush* dst = which == 0 ? q_bf : (which == 1 ? k_bf : v_bf);
#pragma unroll
      for (int r = 0; r < 4; ++r) {
        int ntok = ntok_base + 4 * lq + r;
        dst[((size_t)bh_i * SEQ + ntok) * HD + d] = f2bf(vals[r]);
      }
      if (which < 2) {
        s += __shfl_xor(s, 16);
        s += __shfl_xor(s, 32);
        if (lq == 0) {
          float* lmdst = which == 0 ? qlm : klm;
          lmdst[((size_t)bh_i * NLM + win) * HD + d] = s * (1.0f / LWIN);
        }
      }
    }
  }
}

// ---------------------------------------------------------------------------
// K3: attn2 = softmax(qlm @ klm^T) rows -> split bf16 (a2h/a2l)
// ---------------------------------------------------------------------------
__global__ __launch_bounds__(256) void sim2_softmax(const float* __restrict__ qlm,
                                                    const float* __restrict__ klm,
                                                    ush* __restrict__ a2h,
                                                    ush* __restrict__ a2l) {
  int i = blockIdx.x & 255;
  int bh = blockIdx.x >> 8;
  int j = threadIdx.x;
  __shared__ float qrow[64];
  __shared__ float red[256];
  if (j < 64) qrow[j] = qlm[((size_t)bh * NLM + i) * HD + j];
  __syncthreads();
  const float* kr = klm + ((size_t)bh * NLM + j) * HD;
  float s = 0.f;
#pragma unroll
  for (int d = 0; d < 64; d += 4) {
    float4 kv = *(const float4*)&kr[d];
    s += qrow[d] * kv.x + qrow[d + 1] * kv.y + qrow[d + 2] * kv.z + qrow[d + 3] * kv.w;
  }
  red[j] = s; __syncthreads();
  for (int off = 128; off > 0; off >>= 1) {
    if (j < off) red[j] = fmaxf(red[j], red[j + off]);
    __syncthreads();
  }
  float mx = red[0]; __syncthreads();
  float e = expf(s - mx);
  red[j] = e; __syncthreads();
  for (int off = 128; off > 0; off >>= 1) {
    if (j < off) red[j] += red[j + off];
    __syncthreads();
  }
  float val = e / red[0];
  size_t o = ((size_t)bh * NLM + i) * NLM + j;
  ush h, l; splitf(val, h, l);
  a2h[o] = h; a2l[o] = l;
}

// ---------------------------------------------------------------------------
// K4a: per-bh column/row sums of attn2, block-max of each
// ---------------------------------------------------------------------------
__global__ __launch_bounds__(256) void colrow_max(const ush* __restrict__ a2h,
                                                  const ush* __restrict__ a2l,
                                                  float* __restrict__ red) {
  int bh = blockIdx.x;
  int t = threadIdx.x;
  const size_t base = (size_t)bh * NLM * NLM;
  float cs = 0.f, rs = 0.f;
  for (int i = 0; i < NLM; ++i) {
    size_t o = base + (size_t)i * NLM + t;
    cs += bf2f(a2h[o]) + bf2f(a2l[o]);
  }
  for (int j = 0; j < NLM; ++j) {
    size_t o = base + (size_t)t * NLM + j;
    rs += bf2f(a2h[o]) + bf2f(a2l[o]);
  }
  __shared__ float r1[256], r2[256];
  r1[t] = cs; r2[t] = rs; __syncthreads();
  for (int off = 128; off > 0; off >>= 1) {
    if (t < off) { r1[t] = fmaxf(r1[t], r1[t + off]); r2[t] = fmaxf(r2[t], r2[t + off]); }
    __syncthreads();
  }
  if (t == 0) { red[bh] = r1[0]; red[32 + bh] = r2[0]; }
}

__global__ void finalize_scale(float* __restrict__ red) {
  if (threadIdx.x == 0) {
    float m1 = -1e30f, m2 = -1e30f;
    for (int i = 0; i < BH; ++i) { m1 = fmaxf(m1, red[i]); m2 = fmaxf(m2, red[32 + i]); }
    red[64] = 1.0f / (m1 * m2);
  }
}

// ---------------------------------------------------------------------------
// K4c: z0 = attn2^T * invscale, A-form + B-form splits
// ---------------------------------------------------------------------------
__global__ __launch_bounds__(256) void zinit_split(const ush* __restrict__ a2h,
                                                   const ush* __restrict__ a2l,
                                                   const float* __restrict__ red,
                                                   ush* __restrict__ zAh, ush* __restrict__ zAl,
                                                   ush* __restrict__ zBh, ush* __restrict__ zBl) {
  __shared__ float T[32][33];
  const int tid = threadIdx.x;
  const int bh = blockIdx.z;
  const int j0 = blockIdx.x * 32, i0 = blockIdx.y * 32;
  const float s = red[64];
  const size_t base = (size_t)bh * NLM * NLM;
#pragma unroll
  for (int u = 0; u < 4; ++u) {
    int jl = (tid >> 5) * 4 + u, il = tid & 31;
    size_t o = base + (size_t)(j0 + jl) * NLM + i0 + il;
    float a = (bf2f(a2h[o]) + bf2f(a2l[o])) * s;
    T[jl][il] = a;
    ush h, l; splitf(a, h, l);
    zBh[o] = h; zBl[o] = l;   // zB[j][i] = a2[j][i]*s
  }
  __syncthreads();
#pragma unroll
  for (int u = 0; u < 4; ++u) {
    int il = (tid >> 5) * 4 + u, jl = tid & 31;
    float a = T[jl][il];
    ush h, l; splitf(a, h, l);
    size_t o = base + (size_t)(i0 + il) * NLM + j0 + jl;  // zA[i][j] = a2[j][i]*s
    zAh[o] = h; zAl[o] = l;
  }
}

// ---------------------------------------------------------------------------
// K5: pinv workhorse (round 7): m97-style global_load_lds staging.
// BM=BN=64, BK=64 -> grid (M/64, N/64, 32) = 512 blocks. Single LDS buffer,
// fragment-major planes [op][hl][chunk][64][8] written by the DMA (wave-
// uniform base + lane*16). Per wave per tile: 8 global_load_lds issues,
// 16 ds_read_b128, 24 MFMA. 4 tiles at K=256.
//   C = A@B (split 3-product), Y = coef*(alpha*(Eh+El) - C)
// ---------------------------------------------------------------------------
__global__ __launch_bounds__(256) void bgemm_split(
    const ush* __restrict__ Ah, const ush* __restrict__ Al,
    const ush* __restrict__ Bh, const ush* __restrict__ Bl,
    const ush* __restrict__ Eh, const ush* __restrict__ El,
    ush* oAh, ush* oAl, ush* oBh, ush* oBl,
    int M, int N, int K, float alpha, float coef) {
  __shared__ ush S[2][2][8][64][8];   // [op][hl][kchunk][row][8] = 32 KB
  const int batch = blockIdx.z;
  const size_t abase = (size_t)batch * M * K;
  const size_t bbase = (size_t)batch * N * K;
  const size_t ebase = (size_t)batch * M * N;
  const int tid = threadIdx.x;
  const int w = tid >> 6, lane = tid & 63;
  const int lm = lane & 15, lq = lane >> 4;
  const int wm = w >> 1, wn = w & 1;
  const int row0 = blockIdx.x * 64, col0 = blockIdx.y * 64;
  const ffrag fz = {0.f, 0.f, 0.f, 0.f};
  ffrag acc[2][2] = {{fz, fz}, {fz, fz}};

  const ush* gA[2] = {Ah, Al};
  const ush* gB[2] = {Bh, Bl};
  const size_t arow = abase + (size_t)(row0 + lane) * K;   // per-lane
  const size_t brow = bbase + (size_t)(col0 + lane) * K;

  for (int k0 = 0; k0 < K; k0 += 64) {
    __syncthreads();
    // wave w stages k-chunks {2w, 2w+1} for A and B, hi and lo
#pragma unroll
    for (int hl = 0; hl < 2; ++hl)
#pragma unroll
      for (int ci = 0; ci < 2; ++ci) {
        int c = 2 * w + ci;
        gl_lds16(&gA[hl][arow + k0 + 8 * c], &S[0][hl][c][0][0]);
        gl_lds16(&gB[hl][brow + k0 + 8 * c], &S[1][hl][c][0][0]);
      }
    __syncthreads();   // compiler emits vmcnt(0) drain here (m97 structure)
#pragma unroll
    for (int ks = 0; ks < 2; ++ks) {
      bfrag ah[2], al[2], bhf[2], blf[2];
#pragma unroll
      for (int mt = 0; mt < 2; ++mt) {
        ah[mt] = *(const bfrag*)&S[0][0][4 * ks + lq][32 * wm + 16 * mt + lm][0];
        al[mt] = *(const bfrag*)&S[0][1][4 * ks + lq][32 * wm + 16 * mt + lm][0];
      }
#pragma unroll
      for (int nt = 0; nt < 2; ++nt) {
        bhf[nt] = *(const bfrag*)&S[1][0][4 * ks + lq][32 * wn + 16 * nt + lm][0];
        blf[nt] = *(const bfrag*)&S[1][1][4 * ks + lq][32 * wn + 16 * nt + lm][0];
      }
#pragma unroll
      for (int mt = 0; mt < 2; ++mt)
#pragma unroll
        for (int nt = 0; nt < 2; ++nt) {
          acc[mt][nt] = __builtin_amdgcn_mfma_f32_16x16x32_bf16(ah[mt], bhf[nt], acc[mt][nt], 0, 0, 0);
          acc[mt][nt] = __builtin_amdgcn_mfma_f32_16x16x32_bf16(al[mt], bhf[nt], acc[mt][nt], 0, 0, 0);
          acc[mt][nt] = __builtin_amdgcn_mfma_f32_16x16x32_bf16(ah[mt], blf[nt], acc[mt][nt], 0, 0, 0);
        }
    }
  }
#pragma unroll
  for (int mt = 0; mt < 2; ++mt)
#pragma unroll
    for (int nt = 0; nt < 2; ++nt) {
      int n = col0 + 32 * wn + 16 * nt + lm;
#pragma unroll
      for (int r = 0; r < 4; ++r) {
        int m = row0 + 32 * wm + 16 * mt + 4 * lq + r;
        float c = acc[mt][nt][r];
        float y;
        if (Eh) {
          size_t eo = ebase + (size_t)m * N + n;
          float e = bf2f(Eh[eo]) + bf2f(El[eo]);
          y = coef * (alpha * e - c);
        } else {
          y = -coef * c;
        }
        ush h, l; splitf(y, h, l);
        if (oAh) {
          size_t o = ebase + (size_t)m * N + n;
          oAh[o] = h; oAl[o] = l;
        }
        if (oBh) {
          size_t o = (size_t)batch * N * M + (size_t)n * M + m;
          oBh[o] = h;
          if (oBl) oBl[o] = l;
        }
      }
    }
}

// ---------------------------------------------------------------------------
// vT_cvt_bf: v_bf [bh][n][d] -> vT_bf [bh][d][n]. grid (64, 32)
// ---------------------------------------------------------------------------
__global__ __launch_bounds__(256) void vT_cvt_bf(const ush* __restrict__ v_bf,
                                                 ush* __restrict__ vT) {
  __shared__ ush T[64][72];
  const int bh = blockIdx.y;
  const int n0 = blockIdx.x * 64;
  const int tid = threadIdx.x;
  {
    int n = tid >> 2, off = (tid & 3) * 16;
    const ush* src = &v_bf[((size_t)bh * SEQ + n0 + n) * HD + off];
    *(us8*)&T[n][off] = *(const us8*)src;
    *(us8*)&T[n][off + 8] = *(const us8*)&src[8];
  }
  __syncthreads();
  {
    int d = tid >> 2, noff = (tid & 3) * 16;
    us8 o0, o1;
#pragma unroll
    for (int j = 0; j < 8; ++j) o0[j] = T[noff + j][d];
#pragma unroll
    for (int j = 0; j < 8; ++j) o1[j] = T[noff + 8 + j][d];
    ush* dst = &vT[((size_t)bh * HD + d) * SEQ + n0 + noff];
    *(us8*)dst = o0;
    *(us8*)&dst[8] = o1;
  }
}

// ---------------------------------------------------------------------------
// K6: sim3 flash via MFMA, no max-subtraction (scores tiny). n-split NCH ways.
// ---------------------------------------------------------------------------
constexpr int NCH = 4;
__global__ __launch_bounds__(256) void sim3_mfma(const float* __restrict__ qlm,
                                                 const ush* __restrict__ k_bf,
                                                 const ush* __restrict__ vT_bf,
                                                 float* __restrict__ O_part,
                                                 float* __restrict__ l_part) {
  constexpr int CHUNK = SEQ / NCH;  // 1024
  __shared__ ush Qs[64][72];
  __shared__ ush Ks[128][72];
  __shared__ ush Vs[64][136];
  __shared__ ush Ps[64][136];
  const int bh = blockIdx.z;
  const int m0 = blockIdx.x * 64;
  const int n_base = blockIdx.y * CHUNK;
  const int tid = threadIdx.x;
  const int w = tid >> 6, lane = tid & 63;
  const int lm = lane & 15, lq = lane >> 4;
  {
    int m = tid >> 2, off = (tid & 3) * 16;
    const float* src = &qlm[((size_t)bh * NLM + m0 + m) * HD + off];
    us8 o0, o1;
#pragma unroll
    for (int j = 0; j < 8; ++j) o0[j] = f2bf(src[j]);
#pragma unroll
    for (int j = 0; j < 8; ++j) o1[j] = f2bf(src[8 + j]);
    *(us8*)&Qs[m][off] = o0;
    *(us8*)&Qs[m][off + 8] = o1;
  }
  const ffrag fz = {0.f, 0.f, 0.f, 0.f};
  ffrag O[4] = {fz, fz, fz, fz};
  float lsum[4] = {0.f, 0.f, 0.f, 0.f};

  for (int n0 = 0; n0 < CHUNK; n0 += 128) {
    __syncthreads();
    {
      int n = tid >> 1, off = (tid & 1) * 32;
      const ush* src = &k_bf[((size_t)bh * SEQ + n_base + n0 + n) * HD + off];
#pragma unroll
      for (int u = 0; u < 4; ++u) *(us8*)&Ks[n][off + 8 * u] = *(const us8*)&src[8 * u];
    }
    {
      int d = tid >> 2, off = (tid & 3) * 32;
      const ush* src = &vT_bf[((size_t)bh * HD + d) * SEQ + n_base + n0 + off];
#pragma unroll
      for (int u = 0; u < 4; ++u) *(us8*)&Vs[d][off + 8 * u] = *(const us8*)&src[8 * u];
    }
    __syncthreads();
    ffrag S[8] = {fz, fz, fz, fz, fz, fz, fz, fz};
#pragma unroll
    for (int ks = 0; ks < 2; ++ks) {
      bfrag a = *(const bfrag*)&Qs[16 * w + lm][32 * ks + 8 * lq];
#pragma unroll
      for (int t = 0; t < 8; ++t) {
        bfrag b = *(const bfrag*)&Ks[16 * t + lm][32 * ks + 8 * lq];
        S[t] = __builtin_amdgcn_mfma_f32_16x16x32_bf16(a, b, S[t], 0, 0, 0);
      }
    }
#pragma unroll
    for (int t = 0; t < 8; ++t)
#pragma unroll
      for (int r = 0; r < 4; ++r) {
        float p = __expf(S[t][r]);
        lsum[r] += p;
        Ps[16 * w + 4 * lq + r][16 * t + lm] = f2bf(p);
      }
    __syncthreads();
#pragma unroll
    for (int kk = 0; kk < 4; ++kk) {
      bfrag a = *(const bfrag*)&Ps[16 * w + lm][32 * kk + 8 * lq];
#pragma unroll
      for (int t2 = 0; t2 < 4; ++t2) {
        bfrag b = *(const bfrag*)&Vs[16 * t2 + lm][32 * kk + 8 * lq];
        O[t2] = __builtin_amdgcn_mfma_f32_16x16x32_bf16(a, b, O[t2], 0, 0, 0);
      }
    }
  }
#pragma unroll
  for (int r = 0; r < 4; ++r) {
#pragma unroll
    for (int off = 1; off < 16; off <<= 1) lsum[r] += __shfl_xor(lsum[r], off);
  }
  const size_t pbase = (size_t)blockIdx.y * 32 + bh;
  if (lm == 0) {
#pragma unroll
    for (int r = 0; r < 4; ++r)
      l_part[pbase * NLM + m0 + 16 * w + 4 * lq + r] = lsum[r];
  }
#pragma unroll
  for (int t2 = 0; t2 < 4; ++t2)
#pragma unroll
    for (int r = 0; r < 4; ++r) {
      int m = m0 + 16 * w + 4 * lq + r;
      int d = 16 * t2 + lm;
      O_part[(pbase * NLM + m) * HD + d] = O[t2][r];
    }
}

// sim3_finalize: combine partials, write sv in B-form split ([d][m]).
__global__ __launch_bounds__(256) void sim3_finalize(const float* __restrict__ O_part,
                                                     const float* __restrict__ l_part,
                                                     ush* __restrict__ svBh,
                                                     ush* __restrict__ svBl) {
  __shared__ float acc[256 * 65];
  __shared__ float ls[256];
  const int bh = blockIdx.x;
  const int tid = threadIdx.x;
  for (int e = tid; e < 16384; e += 256) {
    float s = 0.f;
#pragma unroll
    for (int c = 0; c < NCH; ++c) s += O_part[(((size_t)(c * 32 + bh)) << 14) + e];
    acc[(e >> 6) * 65 + (e & 63)] = s;
  }
  {
    float s = 0.f;
#pragma unroll
    for (int c = 0; c < NCH; ++c) s += l_part[(size_t)(c * 32 + bh) * NLM + tid];
    ls[tid] = s;
  }
  __syncthreads();
  for (int e = tid; e < 16384; e += 256) {
    int d = e >> 8, m = e & 255;
    float val = acc[m * 65 + d] / ls[m];
    ush h, l; splitf(val, h, l);
    size_t o = ((size_t)bh * HD + d) * NLM + m;
    svBh[o] = h; svBl[o] = l;
  }
}

// ---------------------------------------------------------------------------
// K8: attn1 via MFMA: outp = softmax(q_bf @ klm^T) @ tt  (fp32 softmax)
// ---------------------------------------------------------------------------
__global__ __launch_bounds__(256) void attn1_mfma(const ush* __restrict__ q_bf,
                                                  const float* __restrict__ klm,
                                                  const ush* __restrict__ ttT,
                                                  float* __restrict__ outp) {
  __shared__ ush bufA[256 * 72];   // klm bf16 [256][72] then ttT [64][264]
  __shared__ ush bufB[64 * 264];   // qs [64][72] then Ps [64][264]
  const int bh = blockIdx.y;
  const int b = bh >> 3, h = bh & 7;
  const int i0 = blockIdx.x * 64;
  const int tid = threadIdx.x;
  const int w = tid >> 6, lane = tid & 63;
  const int lm = lane & 15, lq = lane >> 4;
  {
    int m = tid >> 2, off = (tid & 3) * 16;
    const ush* src = &q_bf[((size_t)bh * SEQ + i0 + m) * HD + off];
    *(us8*)&bufB[m * 72 + off] = *(const us8*)src;
    *(us8*)&bufB[m * 72 + off + 8] = *(const us8*)&src[8];
  }
  {
    const float* kb = klm + (size_t)bh * NLM * HD;
#pragma unroll
    for (int u = 0; u < 16; ++u) {
      int e4 = u * 256 + tid;
      float4 f = ((const float4*)kb)[e4];
      int row = e4 >> 4, col = (e4 & 15) * 4;
      ush* p = &bufA[row * 72 + col];
      p[0] = f2bf(f.x); p[1] = f2bf(f.y); p[2] = f2bf(f.z); p[3] = f2bf(f.w);
    }
  }
  __syncthreads();
  const ffrag fz = {0.f, 0.f, 0.f, 0.f};
  ffrag S[16];
#pragma unroll
  for (int t = 0; t < 16; ++t) S[t] = fz;
#pragma unroll
  for (int ks = 0; ks < 2; ++ks) {
    bfrag a = *(const bfrag*)&bufB[(16 * w + lm) * 72 + 32 * ks + 8 * lq];
#pragma unroll
    for (int t = 0; t < 16; ++t) {
      bfrag bb = *(const bfrag*)&bufA[(16 * t + lm) * 72 + 32 * ks + 8 * lq];
      S[t] = __builtin_amdgcn_mfma_f32_16x16x32_bf16(a, bb, S[t], 0, 0, 0);
    }
  }
  float rinv[4];
  float ev[16][4];
#pragma unroll
  for (int r = 0; r < 4; ++r) {
    float mx = -INFINITY;
#pragma unroll
    for (int t = 0; t < 16; ++t) mx = fmaxf(mx, S[t][r]);
#pragma unroll
    for (int off = 1; off < 16; off <<= 1) mx = fmaxf(mx, __shfl_xor(mx, off));
    float sm = 0.f;
#pragma unroll
    for (int t = 0; t < 16; ++t) { ev[t][r] = __expf(S[t][r] - mx); sm += ev[t][r]; }
#pragma unroll
    for (int off = 1; off < 16; off <<= 1) sm += __shfl_xor(sm, off);
    rinv[r] = 1.0f / sm;
  }
  __syncthreads();
#pragma unroll
  for (int t = 0; t < 16; ++t)
#pragma unroll
    for (int r = 0; r < 4; ++r)
      bufB[(16 * w + 4 * lq + r) * 264 + 16 * t + lm] = f2bf(ev[t][r]);
  {
    const ush* tb = ttT + (size_t)bh * HD * NLM;
#pragma unroll
    for (int u = 0; u < 8; ++u) {
      int e8 = u * 256 + tid;
      int row = e8 >> 5, col = (e8 & 31) * 8;
      *(us8*)&bufA[row * 264 + col] = *(const us8*)&tb[row * NLM + col];
    }
  }
  __syncthreads();
  ffrag O[4] = {fz, fz, fz, fz};
#pragma unroll
  for (int kk = 0; kk < 8; ++kk) {
    bfrag a = *(const bfrag*)&bufB[(16 * w + lm) * 264 + 32 * kk + 8 * lq];
#pragma unroll
    for (int t2 = 0; t2 < 4; ++t2) {
      bfrag bb = *(const bfrag*)&bufA[(16 * t2 + lm) * 264 + 32 * kk + 8 * lq];
      O[t2] = __builtin_amdgcn_mfma_f32_16x16x32_bf16(a, bb, O[t2], 0, 0, 0);
    }
  }
#pragma unroll
  for (int t2 = 0; t2 < 4; ++t2)
#pragma unroll
    for (int r = 0; r < 4; ++r) {
      int i = i0 + 16 * w + 4 * lq + r;
      int d = 16 * t2 + lm;
      outp[((size_t)b * SEQ + i) * DIMC + h * HD + d] = O[t2][r] * rinv[r];
    }
}

// ---------------------------------------------------------------------------
// K9: conv add + split: outp(fp32) + depthwise conv(vT_bf) -> outph/outpl
// ---------------------------------------------------------------------------
__global__ __launch_bounds__(256) void conv_add_split(const float* __restrict__ outp,
                                                      const ush* __restrict__ vT,
                                                      const float* __restrict__ kern,
                                                      ush* __restrict__ oh,
                                                      ush* __restrict__ ol) {
  __shared__ float vt[64 * 97];   // [d][96+1], cols n0-16 .. n0+79
  __shared__ float ks[KWIN];
  const int bh = blockIdx.y;
  const int b = bh >> 3, hh = bh & 7;
  const int n0 = blockIdx.x * 64;
  const int tid = threadIdx.x;
  if (tid < KWIN) ks[tid] = kern[hh * KWIN + tid];
  for (int e = tid; e < 64 * 96; e += 256) {
    int d = e / 96, c = e % 96;
    int n = n0 - 16 + c;
    vt[d * 97 + c] = (n >= 0 && n < SEQ) ? bf2f(vT[((size_t)bh * HD + d) * SEQ + n]) : 0.f;
  }
  __syncthreads();
  const int d = tid & 63, g = tid >> 6;
  float wreg[48];
#pragma unroll
  for (int j = 0; j < 48; ++j) wreg[j] = vt[d * 97 + g * 16 + j];
#pragma unroll
  for (int nn = 0; nn < 16; ++nn) {
    float s = 0.f;
#pragma unroll
    for (int t = 0; t < KWIN; ++t) s = fmaf(ks[t], wreg[nn + t], s);
    int n = n0 + g * 16 + nn;
    size_t o = ((size_t)b * SEQ + n) * DIMC + hh * HD + d;
    float val = outp[o] + s;
    ush h, l; splitf(val, h, l);
    oh[o] = h; ol[o] = l;
  }
}

// ---------------------------------------------------------------------------
// K10: out = outp_split @ WoutT_split + bias — ROUND-5 LAYOUT (reverted).
// BM=BN=128, grid (128, 4)
// ---------------------------------------------------------------------------
__global__ __launch_bounds__(256) void out_gemm_split(const ush* __restrict__ ah_g,
                                                      const ush* __restrict__ al_g,
                                                      const ush* __restrict__ bh_g,
                                                      const ush* __restrict__ bl_g,
                                                      const float* __restrict__ bias,
                                                      float* __restrict__ out) {
  __shared__ ush Ash[128][40], Asl[128][40];
  __shared__ ush Bsh[128][40], Bsl[128][40];
  const int tid = threadIdx.x;
  const int w = tid >> 6, lane = tid & 63;
  const int lm = lane & 15, lq = lane >> 4;
  const int wm = w >> 1, wn = w & 1;
  const int row0 = blockIdx.x * 128, col0 = blockIdx.y * 128;
  const ffrag fz = {0.f, 0.f, 0.f, 0.f};
  ffrag acc[4][4];
#pragma unroll
  for (int i = 0; i < 4; ++i)
#pragma unroll
    for (int j = 0; j < 4; ++j) acc[i][j] = fz;

  const int sm = tid >> 1, skoff = (tid & 1) * 16;
  for (int k0 = 0; k0 < 512; k0 += 32) {
    __syncthreads();
    {
      size_t ao = (size_t)(row0 + sm) * 512 + k0 + skoff;
      *(us8*)&Ash[sm][skoff]     = *(const us8*)&ah_g[ao];
      *(us8*)&Ash[sm][skoff + 8] = *(const us8*)&ah_g[ao + 8];
      *(us8*)&Asl[sm][skoff]     = *(const us8*)&al_g[ao];
      *(us8*)&Asl[sm][skoff + 8] = *(const us8*)&al_g[ao + 8];
      size_t bo = (size_t)(col0 + sm) * 512 + k0 + skoff;
      *(us8*)&Bsh[sm][skoff]     = *(const us8*)&bh_g[bo];
      *(us8*)&Bsh[sm][skoff + 8] = *(const us8*)&bh_g[bo + 8];
      *(us8*)&Bsl[sm][skoff]     = *(const us8*)&bl_g[bo];
      *(us8*)&Bsl[sm][skoff + 8] = *(const us8*)&bl_g[bo + 8];
    }
    __syncthreads();
    bfrag ah[4], al[4], bh[4], bl[4];
#pragma unroll
    for (int mt = 0; mt < 4; ++mt) {
      ah[mt] = *(const bfrag*)&Ash[64 * wm + 16 * mt + lm][8 * lq];
      al[mt] = *(const bfrag*)&Asl[64 * wm + 16 * mt + lm][8 * lq];
    }
#pragma unroll
    for (int nt = 0; nt < 4; ++nt) {
      bh[nt] = *(const bfrag*)&Bsh[64 * wn + 16 * nt + lm][8 * lq];
      bl[nt] = *(const bfrag*)&Bsl[64 * wn + 16 * nt + lm][8 * lq];
    }
#pragma unroll
    for (int mt = 0; mt < 4; ++mt)
#pragma unroll
      for (int nt = 0; nt < 4; ++nt) {
        acc[mt][nt] = __builtin_amdgcn_mfma_f32_16x16x32_bf16(ah[mt], bh[nt], acc[mt][nt], 0, 0, 0);
        acc[mt][nt] = __builtin_amdgcn_mfma_f32_16x16x32_bf16(al[mt], bh[nt], acc[mt][nt], 0, 0, 0);
        acc[mt][nt] = __builtin_amdgcn_mfma_f32_16x16x32_bf16(ah[mt], bl[nt], acc[mt][nt], 0, 0, 0);
      }
  }
#pragma unroll
  for (int mt = 0; mt < 4; ++mt)
#pragma unroll
    for (int nt = 0; nt < 4; ++nt) {
      int n = col0 + 64 * wn + 16 * nt + lm;
      float bv = bias[n];
#pragma unroll
      for (int r = 0; r < 4; ++r) {
        int m = row0 + 64 * wm + 16 * mt + 4 * lq + r;
        out[(size_t)m * 512 + n] = acc[mt][nt][r] + bv;
      }
    }
}

// ---------------------------------------------------------------------------
extern "C" void kernel_launch(void* const* d_in, const int* in_sizes, int n_in,
                              void* d_out, int out_size, void* d_ws, size_t ws_size,
                              hipStream_t stream) {
  const float* x    = (const float*)d_in[0];
  const float* Wqkv = (const float*)d_in[1];
  const float* Wout = (const float*)d_in[2];
  const float* bout = (const float*)d_in[3];
  const float* rker = (const float*)d_in[4];
  float* out = (float*)d_out;
  float* ws = (float*)d_ws;

  // workspace layout (float-element offsets), total ~186.6 MB
  ush*   v_bf   = (ush*)(ws);                          // 8388608 ush (4194304 f)
  ush*   q_bf   = (ush*)(ws + 4194304);                // 8388608 ush
  float* regA   = ws + 8388608;                        // 8388608 f: k_bf -> outp
  float* regB   = ws + 16777216;                       // 8388608 f: xh+xl -> outph+outpl
  float* qlm    = ws + 25165824;                       // 524288
  float* klm    = ws + 25690112;                       // 524288
  float* regC   = ws + 26214400;                       // 2097152 f: t2B(h,l) / ttT
  float* a2reg  = ws + 28311552;                       // 2097152 f: a2h+a2l
  float* zAreg  = ws + 30408704;                       // 4194304 f
  float* zBreg  = ws + 34603008;                       // 4194304 f (later vT_bf)
  float* xzreg  = ws + 38797312;                       // 4194304 f (later O_part/l_part)
  float* t3reg  = ws + 43515904;                       // 2097152 f (later svB)
  float* wqkvT  = ws + 45613056;                       // 786432 f
  float* woutT  = ws + 46399488;                       // 262144 f
  float* red    = ws + 46661632;                       // 128

  ush* k_bf  = (ush*)regA;
  float* outp = regA;
  ush* xh = (ush*)regB;                 // 8388608 ush
  ush* xl = (ush*)(regB + 4194304);     // 8388608 ush
  ush* outph = (ush*)regB;
  ush* outpl = (ush*)(regB + 4194304);
  ush* a2h = (ush*)a2reg;               // 2097152 ush each
  ush* a2l = (ush*)(a2reg + 1048576);
  ush* zA_[4] = {(ush*)zAreg, (ush*)(zAreg + 1048576), (ush*)(zAreg + 2097152), (ush*)(zAreg + 3145728)};
  ush* zB_[4] = {(ush*)zBreg, (ush*)(zBreg + 1048576), (ush*)(zBreg + 2097152), (ush*)(zBreg + 3145728)};
  ush* xzA_h = (ush*)xzreg;
  ush* xzA_l = (ush*)(xzreg + 1048576);
  ush* xzB_h = (ush*)(xzreg + 2097152);
  ush* xzB_l = (ush*)(xzreg + 3145728);
  ush* t2B_h = (ush*)regC;
  ush* t2B_l = (ush*)(regC + 1048576);
  ush* t3B_h = (ush*)t3reg;
  ush* t3B_l = (ush*)(t3reg + 1048576);
  ush* vT_bf = (ush*)zBreg;             // after pinv
  float* O_part = xzreg;                // after pinv
  float* l_part = xzreg + 2097152;
  ush* svB_h = (ush*)t3reg;             // after pinv
  ush* svB_l = (ush*)(t3reg + 262144);
  ush* ttT   = (ush*)regC;              // after pinv
  ush* wqkvT_h = (ush*)wqkvT;
  ush* wqkvT_l = (ush*)(wqkvT + 393216);
  ush* woutT_h = (ush*)woutT;
  ush* woutT_l = (ush*)(woutT + 131072);

  // --- pre-splits ---
  split_flat<<<8192, 256, 0, stream>>>(x, xh, xl, 2097152);
  transpose_split_w<<<dim3(48, 16), 256, 0, stream>>>(Wqkv, wqkvT_h, wqkvT_l, 512, 1536);
  transpose_split_w<<<dim3(16, 16), 256, 0, stream>>>(Wout, woutT_h, woutT_l, 512, 512);

  // --- qkv + landmarks ---
  qkv_mfma<<<dim3(128, 12), 256, 0, stream>>>(xh, xl, wqkvT_h, wqkvT_l,
                                              q_bf, k_bf, v_bf, qlm, klm);

  // --- attn2 + pinv init ---
  sim2_softmax<<<8192, 256, 0, stream>>>(qlm, klm, a2h, a2l);
  colrow_max<<<32, 256, 0, stream>>>(a2h, a2l, red);
  finalize_scale<<<1, 64, 0, stream>>>(red);
  zinit_split<<<dim3(8, 8, 32), 256, 0, stream>>>(a2h, a2l, red,
                                                  zA_[0], zA_[1], zA_[2], zA_[3]);

  // --- pinv Newton-Schulz (split-bf16, global_load_lds staging) ---
  ush** zc = zA_;
  ush** zn = zB_;
  for (int it = 0; it < 6; ++it) {
    bgemm_split<<<dim3(4, 4, 32), 256, 0, stream>>>(
        a2h, a2l, zc[2], zc[3], nullptr, nullptr,
        xzA_h, xzA_l, xzB_h, xzB_l, 256, 256, 256, 0.f, -1.f);
    bgemm_split<<<dim3(4, 4, 32), 256, 0, stream>>>(
        xzA_h, xzA_l, xzB_h, xzB_l, xzA_h, xzA_l,
        nullptr, nullptr, t2B_h, t2B_l, 256, 256, 256, 7.f, 1.f);
    bgemm_split<<<dim3(4, 4, 32), 256, 0, stream>>>(
        xzA_h, xzA_l, t2B_h, t2B_l, xzA_h, xzA_l,
        nullptr, nullptr, t3B_h, t3B_l, 256, 256, 256, 15.f, 1.f);
    bgemm_split<<<dim3(4, 4, 32), 256, 0, stream>>>(
        zc[0], zc[1], t3B_h, t3B_l, zc[0], zc[1],
        zn[0], zn[1], zn[2], zn[3], 256, 256, 256, 13.f, 0.25f);
    ush** tp = zc; zc = zn; zn = tp;
  }
  // after 6 swaps zc == zA_ (attn2_inv)

  // --- sim3 (flash) ---
  vT_cvt_bf<<<dim3(64, 32), 256, 0, stream>>>(v_bf, vT_bf);
  sim3_mfma<<<dim3(4, NCH, 32), 256, 0, stream>>>(qlm, k_bf, vT_bf, O_part, l_part);
  sim3_finalize<<<32, 256, 0, stream>>>(O_part, l_part, svB_h, svB_l);

  // --- tt = attn2_inv @ sv (write ttT = tt^T plain bf16) ---
  bgemm_split<<<dim3(4, 1, 32), 256, 0, stream>>>(
      zc[0], zc[1], svB_h, svB_l, nullptr, nullptr,
      nullptr, nullptr, ttT, nullptr, 256, 64, 256, 0.f, -1.f);

  // --- attn1 + conv + output projection ---
  attn1_mfma<<<dim3(64, 32), 256, 0, stream>>>(q_bf, klm, ttT, outp);
  conv_add_split<<<dim3(64, 32), 256, 0, stream>>>(outp, vT_bf, rker, outph, outpl);
  out_gemm_split<<<dim3(128, 4), 256, 0, stream>>>(outph, outpl, woutT_h, woutT_l, bout, out);
}